// Round 10
// baseline (558.460 us; speedup 1.0000x reference)
//
#include <hip/hip_runtime.h>
#include <stdint.h>

typedef unsigned int u32;
typedef unsigned long long u64;
typedef __attribute__((ext_vector_type(8))) short v8s;   // 8 bf16 = 4 VGPR (MFMA A/B frag)
typedef __attribute__((ext_vector_type(4))) float v4f;   // MFMA C/D frag

#define HH 64
#define WW 96
#define HW 6144
#define CC 512
#define NANCH 55296
#define PRE 6000
#define POST 300
#define CAP 8192
#define PW 98
#define PH 66
#define ICPAD 40
#define NHB 384          // k_head blocks (hist8g partials)
#define NW 94            // suppression-mask words per row: ceil(PRE/64)

__device__ __constant__ float c_aw[9] = {184.f,368.f,736.f,128.f,256.f,512.f,88.f,176.f,352.f};
__device__ __constant__ float c_ah[9] = {96.f,192.f,384.f,128.f,256.f,512.f,176.f,352.f,704.f};

__device__ __forceinline__ unsigned short bf16_rne(float x){
  u32 u = __float_as_uint(x);
  return (unsigned short)((u + 0x7FFFu + ((u >> 16) & 1u)) >> 16);
}
__device__ __forceinline__ u32 sortkey(float s){
  u32 u = __float_as_uint(s);
  return u ^ ((u & 0x80000000u) ? 0xFFFFFFFFu : 0x80000000u);
}

// ---------- K0: merged convert + zeroing — R29: u64-packed bf16 hi/lo stores ----------
__global__ __launch_bounds__(256) void k_cvt(const float* __restrict__ X, const float* __restrict__ Wt,
                                             const float* __restrict__ cw, const float* __restrict__ bw,
                                             unsigned short* __restrict__ Xih, unsigned short* __restrict__ Xil,
                                             unsigned short* __restrict__ Wh2, unsigned short* __restrict__ Wl2,
                                             float* __restrict__ Whd, u32* __restrict__ zero_region){
  __shared__ float Ls[64][97];
  __shared__ float Ws[4608];
  const int b = blockIdx.x, tid = threadIdx.x;
  { int gid = b*256 + tid;
    if (gid < 163856) zero_region[gid] = 0u; }   // hist8g (98304) + hist2 (65536) + ctr (16)
  if (b < 528){
    const int rp  = b % 66;
    const int ic0 = (b / 66) * 64;
    const bool zrow = (rp == 0 || rp == PH-1);
    if (!zrow){
      int r = rp - 1;
      for (int i = tid; i < 6144; i += 256){
        int ii = i / 96, c = i - ii*96;
        Ls[ii][c] = X[(ic0+ii)*HW + r*WW + c];
      }
    }
    __syncthreads();
    for (int idx = tid; idx < 98*16; idx += 256){
      int cp = idx >> 4, g = idx & 15;
      int icl0 = g*4;
      u64 hv = 0, lv = 0;
      #pragma unroll
      for (int u = 0; u < 4; ++u){
        float x = 0.f;
        if (!zrow && cp >= 1 && cp <= 96) x = Ls[icl0+u][cp-1];
        unsigned short h = bf16_rne(x);
        float hf = __uint_as_float(((u32)h) << 16);
        unsigned short l = bf16_rne(x - hf);
        hv |= ((u64)h) << (16*u);
        lv |= ((u64)l) << (16*u);
      }
      long o = ((long)(rp*PW + cp) << 9) + ic0 + icl0;
      *reinterpret_cast<u64*>(Xih + o) = hv;
      *reinterpret_cast<u64*>(Xil + o) = lv;
    }
  } else if (b < 1040){
    const int oc = b - 528;
    for (int i = tid; i < 4608; i += 256) Ws[i] = Wt[oc*4608 + i];
    __syncthreads();
    for (int idx = tid; idx < 9*128; idx += 256){
      int tap = idx >> 7, g = idx & 127;
      int icb = g*4;
      u64 hv = 0, lv = 0;
      #pragma unroll
      for (int u = 0; u < 4; ++u){
        float x = Ws[(icb+u)*9 + tap];
        unsigned short h = bf16_rne(x);
        float hf = __uint_as_float(((u32)h) << 16);
        unsigned short l = bf16_rne(x - hf);
        hv |= ((u64)h) << (16*u);
        lv |= ((u64)l) << (16*u);
      }
      long o = ((long)(tap*512 + oc) << 9) + icb;
      *reinterpret_cast<u64*>(Wh2 + o) = hv;
      *reinterpret_cast<u64*>(Wl2 + o) = lv;
    }
  } else {
    // head-weight transpose: Whd[gc*64 + o]
    int idx = (b - 1040)*256 + tid;
    int o  = idx >> 9;
    int gc = idx & 511;
    float v = 0.f;
    if (o < 18) v = cw[o*512 + gc];
    else if (o < 54) v = bw[(o-18)*512 + gc];
    Whd[gc*64 + o] = v;
  }
}

// ---------- K1: MFMA conv — R29 K-split (icg 0-7 / 8-15), bit-exact fp32 round-trip ----------
template<bool FIRST, bool LAST>
__global__ __launch_bounds__(256, 1) void k_conv3t(
    const unsigned short* __restrict__ Xih, const unsigned short* __restrict__ Xil,
    const unsigned short* __restrict__ Wh2, const unsigned short* __restrict__ Wl2,
    const float* __restrict__ Bc, float* __restrict__ Y)
{
  __shared__ __attribute__((aligned(16))) unsigned short Ah[6*98*ICPAD];
  __shared__ __attribute__((aligned(16))) unsigned short Al[6*98*ICPAD];
  __shared__ __attribute__((aligned(16))) unsigned short Bh[9*32*ICPAD];
  __shared__ __attribute__((aligned(16))) unsigned short Bl[9*32*ICPAD];
  const int tid  = threadIdx.x;
  const int w    = tid >> 6;
  const int lane = tid & 63;
  const int lm   = lane & 15;
  const int q    = lane >> 4;
  const int y0   = blockIdx.x * 4;
  const int oc0  = blockIdx.y * 32;
  const int yrow = y0 + w;

  v4f acc[6][2];
  if (FIRST){
    #pragma unroll
    for (int t = 0; t < 6; ++t)
      #pragma unroll
      for (int n = 0; n < 2; ++n)
        acc[t][n] = (v4f){0.f,0.f,0.f,0.f};
  } else {
    #pragma unroll
    for (int n = 0; n < 2; ++n){
      int oc = oc0 + n*16 + lm;
      #pragma unroll
      for (int t = 0; t < 6; ++t)
        acc[t][n] = *reinterpret_cast<const v4f*>(Y + (long)oc*HW + yrow*WW + 16*t + q*4);
    }
  }

  const int icg0 = FIRST ? 0 : 8;
  const int icgN = LAST ? 16 : 8;

  u64 ra[19][2], rb[9][2];
  auto loadSlab = [&](int icg){
    #pragma unroll
    for (int n = 0; n < 19; ++n){
      int it = tid + 256*n;
      if (it < 4704){
        int i4 = it & 7, rc = it >> 3;
        int c = rc % 98, r = rc / 98;
        long src = ((long)((y0 + r)*PW + c) << 9) + icg*32 + i4*4;
        ra[n][0] = *reinterpret_cast<const u64*>(Xih + src);
        ra[n][1] = *reinterpret_cast<const u64*>(Xil + src);
      }
    }
    #pragma unroll
    for (int n = 0; n < 9; ++n){
      int it = tid + 256*n;
      if (it < 2304){
        int i4 = it & 7, to = it >> 3;
        int oc = to & 31, tap = to >> 5;
        long src = ((long)(tap*512 + oc0 + oc) << 9) + icg*32 + i4*4;
        rb[n][0] = *reinterpret_cast<const u64*>(Wh2 + src);
        rb[n][1] = *reinterpret_cast<const u64*>(Wl2 + src);
      }
    }
  };
  auto storeSlab = [&](){
    #pragma unroll
    for (int n = 0; n < 19; ++n){
      int it = tid + 256*n;
      if (it < 4704){
        int i4 = it & 7, rc = it >> 3;
        int dst = rc*ICPAD + i4*4;
        *reinterpret_cast<u64*>(Ah + dst) = ra[n][0];
        *reinterpret_cast<u64*>(Al + dst) = ra[n][1];
      }
    }
    #pragma unroll
    for (int n = 0; n < 9; ++n){
      int it = tid + 256*n;
      if (it < 2304){
        int i4 = it & 7, to = it >> 3;
        int dst = to*ICPAD + i4*4;
        *reinterpret_cast<u64*>(Bh + dst) = rb[n][0];
        *reinterpret_cast<u64*>(Bl + dst) = rb[n][1];
      }
    }
  };

  loadSlab(icg0);
  for (int icg = icg0; icg < icgN; ++icg){
    __syncthreads();
    storeSlab();
    __syncthreads();
    if (icg + 1 < icgN) loadSlab(icg + 1);
    #pragma unroll
    for (int tap = 0; tap < 9; ++tap){
      const int dy = tap / 3, dx = tap - dy*3;
      v8s ah[6], al[6], bh[2], bl[2];
      #pragma unroll
      for (int t = 0; t < 6; ++t){
        int a = ((w + dy)*98 + 16*t + lm + dx)*ICPAD + q*8;
        ah[t] = *reinterpret_cast<const v8s*>(Ah + a);
        al[t] = *reinterpret_cast<const v8s*>(Al + a);
      }
      #pragma unroll
      for (int n = 0; n < 2; ++n){
        int a = (tap*32 + n*16 + lm)*ICPAD + q*8;
        bh[n] = *reinterpret_cast<const v8s*>(Bh + a);
        bl[n] = *reinterpret_cast<const v8s*>(Bl + a);
      }
      #pragma unroll
      for (int t = 0; t < 6; ++t)
        #pragma unroll
        for (int n = 0; n < 2; ++n){
          acc[t][n] = __builtin_amdgcn_mfma_f32_16x16x32_bf16(al[t], bl[n], acc[t][n], 0, 0, 0);
          acc[t][n] = __builtin_amdgcn_mfma_f32_16x16x32_bf16(al[t], bh[n], acc[t][n], 0, 0, 0);
          acc[t][n] = __builtin_amdgcn_mfma_f32_16x16x32_bf16(ah[t], bl[n], acc[t][n], 0, 0, 0);
          acc[t][n] = __builtin_amdgcn_mfma_f32_16x16x32_bf16(ah[t], bh[n], acc[t][n], 0, 0, 0);
        }
    }
  }

  #pragma unroll
  for (int n = 0; n < 2; ++n){
    int oc = oc0 + n*16 + lm;
    if (LAST){
      float b = Bc[oc];
      #pragma unroll
      for (int t = 0; t < 6; ++t){
        float4 v;
        v.x = fmaxf(acc[t][n].x + b, 0.f);
        v.y = fmaxf(acc[t][n].y + b, 0.f);
        v.z = fmaxf(acc[t][n].z + b, 0.f);
        v.w = fmaxf(acc[t][n].w + b, 0.f);
        *reinterpret_cast<float4*>(Y + (long)oc*HW + yrow*WW + 16*t + q*4) = v;
      }
    } else {
      #pragma unroll
      for (int t = 0; t < 6; ++t)
        *reinterpret_cast<v4f*>(Y + (long)oc*HW + yrow*WW + 16*t + q*4) = acc[t][n];
    }
  }
}

// ---------------- K2: 1x1 heads + softmax + box decode (R27/R28 proven) ----------------
__global__ __launch_bounds__(256) void k_head(
    const float* __restrict__ Y, const float* __restrict__ Whd,
    const float* __restrict__ cb, const float* __restrict__ bb,
    const float* __restrict__ info,
    float* __restrict__ scores, float4* __restrict__ boxes, u32* __restrict__ hist8g)
{
  __shared__ float Ys[1024];
  __shared__ float Wsh[4096];   // transposed: Wsh[c*64 + (o&15)*4 + (o>>4)] = W[c][o]
  __shared__ u32 lh[256];
  const int tid = threadIdx.x;
  const int p0  = blockIdx.x * 16;
  const int po  = tid & 15;
  const int oj  = tid >> 4;
  lh[tid] = 0u;
  float accM[4], accC[4];
  #pragma unroll
  for (int k = 0; k < 4; ++k){ accM[k] = 0.f; accC[k] = 0.f; }

  for (int c0 = 0; c0 < CC; c0 += 64){
    __syncthreads();
    for (int i = tid; i < 1024; i += 256){
      int c = i >> 4, p = i & 15;
      Ys[i] = Y[(c0 + c) * HW + p0 + p];
    }
    for (int i = tid; i < 4096; i += 256){
      int c = i >> 6, o = i & 63;
      Wsh[c*64 + (o & 15)*4 + (o >> 4)] = Whd[(c0 + c)*64 + o];
    }
    __syncthreads();
    #pragma unroll 4
    for (int c = 0; c < 64; ++c){
      float xa = Ys[c*16 + po];
      float4 wv = *reinterpret_cast<const float4*>(Wsh + c*64 + oj*4);
      accC[0] = __fmaf_rn(xa, wv.x, accC[0]);
      accC[1] = __fmaf_rn(xa, wv.y, accC[1]);
      accC[2] = __fmaf_rn(xa, wv.z, accC[2]);
      accC[3] = __fmaf_rn(xa, wv.w, accC[3]);
    }
    #pragma unroll
    for (int k = 0; k < 4; ++k){ accM[k] += accC[k]; accC[k] = 0.f; }
  }
  __syncthreads();
  #pragma unroll
  for (int k = 0; k < 4; ++k){
    int o = oj + 16*k;
    float bias = (o < 18) ? cb[o] : ((o < 54) ? bb[o - 18] : 0.f);
    Ys[po*64 + o] = accM[k] + bias;
  }
  __syncthreads();
  float imH = info[0], imW = info[1], imS = info[2];
  for (int it = tid; it < 144; it += 256){
    int pl = it / 9;
    int a  = it - pl*9;
    const float* L = Ys + pl*64;
    float l0 = L[a], l1 = L[9 + a];
    float mx = fmaxf(l0, l1);
    float e0 = expf(l0 - mx), e1 = expf(l1 - mx);
    float sc = e1 / (e0 + e1);
    float d0 = L[18 + a*4 + 0], d1 = L[18 + a*4 + 1];
    float d2 = L[18 + a*4 + 2], d3 = L[18 + a*4 + 3];
    int pos = p0 + pl;
    int yy = pos / 96;
    int xx = pos - yy * 96;
    float aw = c_aw[a], ah = c_ah[a];
    float acx = (float)(xx * 16 + 8);
    float acy = (float)(yy * 16 + 8);
    float cx = __fadd_rn(__fmul_rn(d0, aw), acx);
    float cy = __fadd_rn(__fmul_rn(d1, ah), acy);
    float pw = __fmul_rn(expf(d2), aw);
    float ph = __fmul_rn(expf(d3), ah);
    float hx = __fmul_rn(0.5f, pw);
    float hy = __fmul_rn(0.5f, ph);
    float x1 = fminf(fmaxf(__fadd_rn(cx, -hx), 0.f), imW - 1.f);
    float y1 = fminf(fmaxf(__fadd_rn(cy, -hy), 0.f), imH - 1.f);
    float x2 = fminf(fmaxf(__fadd_rn(cx,  hx), 0.f), imW - 1.f);
    float y2 = fminf(fmaxf(__fadd_rn(cy,  hy), 0.f), imH - 1.f);
    float ms = 16.f * imS;
    bool keep = ((x2 - x1 + 1.f) >= ms) && ((y2 - y1 + 1.f) >= ms);
    int g = pos * 9 + a;
    float val = keep ? sc : -__builtin_inff();
    scores[g] = val;
    boxes[g]  = make_float4(x1, y1, x2, y2);
    atomicAdd(&lh[sortkey(val) >> 24], 1u);   // LDS atomic, block-private
  }
  __syncthreads();
  hist8g[blockIdx.x*256 + tid] = lh[tid];     // plain coalesced store
}

// ---------- K3: fused selection — R27 3-level exact radix select (proven) ----------
__global__ __launch_bounds__(1024) void k_sel(const u32* __restrict__ hist8g, u32* __restrict__ hist2,
                                              const float* __restrict__ scores,
                                              u32* __restrict__ ctr, u64* __restrict__ keys){
  __shared__ u32 cs[1024];
  __shared__ u32 bs[64];
  __shared__ u32 h8[256];
  __shared__ u32 lh2[256];
  __shared__ int selg;
  __shared__ u32 afterv, T16s, aboves, K32s, B8s, above8s;
  const int t = threadIdx.x;
  const int b0 = t * 64;

  // ---- L1: merge per-block 256-bin partials ----
  { int g = t >> 8, bin = t & 255;
    u32 s = 0;
    for (int b = g; b < NHB; b += 4) s += hist8g[b*256 + bin];
    cs[t] = s; }
  __syncthreads();
  if (t < 256){
    h8[t] = cs[t] + cs[256 + t] + cs[512 + t] + cs[768 + t];
    lh2[t] = 0u;
  }
  __syncthreads();
  if (t == 0){
    u32 acc = 0;
    for (int bin = 255; bin >= 0; --bin){
      acc += h8[bin];
      if (acc >= 6000u){ B8s = (u32)bin; above8s = acc - h8[bin]; break; }
    }
  }
  __syncthreads();

  // ---- L2: 256-bin scan over next 8 bits among keys with top8 == B8 ----
  { u32 b8 = B8s;
    const float4* s4 = reinterpret_cast<const float4*>(scores);
    for (int i = t; i < NANCH/4; i += 1024){
      float4 v = s4[i];
      u32 k0 = sortkey(v.x), k1 = sortkey(v.y), k2 = sortkey(v.z), k3 = sortkey(v.w);
      if ((k0 >> 24) == b8) atomicAdd(&lh2[(k0 >> 16) & 0xFFu], 1u);
      if ((k1 >> 24) == b8) atomicAdd(&lh2[(k1 >> 16) & 0xFFu], 1u);
      if ((k2 >> 24) == b8) atomicAdd(&lh2[(k2 >> 16) & 0xFFu], 1u);
      if ((k3 >> 24) == b8) atomicAdd(&lh2[(k3 >> 16) & 0xFFu], 1u);
    } }
  __syncthreads();
  if (t == 0){
    u32 acc = above8s;
    for (int bin = 255; bin >= 0; --bin){
      acc += lh2[bin];
      if (acc >= 6000u){ T16s = (B8s << 8) | (u32)bin; aboves = acc - lh2[bin]; break; }
    }
  }
  __syncthreads();

  // ---- L3: hist2 over low 16 bits among keys with top16 == T16s ----
  { u32 pfx = T16s;
    const float4* s4 = reinterpret_cast<const float4*>(scores);
    for (int i = t; i < NANCH/4; i += 1024){
      float4 v = s4[i];
      u32 k0 = sortkey(v.x), k1 = sortkey(v.y), k2 = sortkey(v.z), k3 = sortkey(v.w);
      if ((k0 >> 16) == pfx) atomicAdd(&hist2[k0 & 0xFFFFu], 1u);
      if ((k1 >> 16) == pfx) atomicAdd(&hist2[k1 & 0xFFFFu], 1u);
      if ((k2 >> 16) == pfx) atomicAdd(&hist2[k2 & 0xFFFFu], 1u);
      if ((k3 >> 16) == pfx) atomicAdd(&hist2[k3 & 0xFFFFu], 1u);
    } }
  __threadfence();
  __syncthreads();

  if (t == 0) selg = -1;
  __syncthreads();
  const u32 target = 6000u - aboves;
  { u32 s = 0;
    for (int i = 0; i < 64; ++i) s += hist2[b0 + i];
    cs[t] = s; }
  __syncthreads();
  for (int off = 1; off < 1024; off <<= 1){
    u32 v = cs[t];
    u32 ad = (t + off < 1024) ? cs[t + off] : 0u;
    __syncthreads();
    cs[t] = v + ad;
    __syncthreads();
  }
  { u32 here  = cs[t];
    u32 after = (t < 1023) ? cs[t + 1] : 0u;
    if (here >= target && after < target){ selg = t; afterv = after; } }
  __syncthreads();
  { int g = selg;
    if (g >= 0 && t < 64) bs[t] = hist2[g*64 + t];
    __syncthreads();
    if (t == 0){
      if (g < 0) K32s = (T16s << 16);
      else {
        u32 acc = afterv;
        for (int b = 63; b >= 0; --b){
          u32 h = bs[b];
          acc += h;
          if (acc >= target){ K32s = (T16s << 16) | (u32)(g*64 + b); break; }
        }
      }
      ctr[4] = 6000u;
    } }
  __syncthreads();

  // ---- compact: ballot-aggregated counter ----
  { u32 K = K32s;
    const int lane = t & 63;
    const float4* s4 = reinterpret_cast<const float4*>(scores);
    for (int i = t; i < NANCH/4; i += 1024){
      float4 v = s4[i];
      u32 kk[4] = {sortkey(v.x), sortkey(v.y), sortkey(v.z), sortkey(v.w)};
      u64 m[4];
      #pragma unroll
      for (int u = 0; u < 4; ++u) m[u] = __ballot(kk[u] >= K);
      u32 tot = (u32)(__popcll(m[0]) + __popcll(m[1]) + __popcll(m[2]) + __popcll(m[3]));
      if (tot){
        u32 base = 0;
        if (lane == 0) base = atomicAdd(&ctr[0], tot);
        base = (u32)__shfl((int)base, 0, 64);
        u64 below = ((u64)1 << lane) - 1;
        u32 off = 0;
        #pragma unroll
        for (int u = 0; u < 4; ++u){
          if (kk[u] >= K){
            u32 pos = base + off + (u32)__popcll(m[u] & below);
            if (pos < CAP) keys[pos] = ((u64)kk[u] << 32) | (u64)(u32)(~(u32)(i*4 + u));
          }
          off += (u32)__popcll(m[u]);
        }
      }
    } }
}

// ---------------- K-rank — R27: block-reduced atomicMin (proven) ----------------
__global__ __launch_bounds__(512) void k_rank(const u64* __restrict__ keys, u32* __restrict__ ctr,
                                              const float4* __restrict__ boxes,
                                              float4* __restrict__ topB, float* __restrict__ topA){
  __shared__ u64 ks[CAP];        // 64 KB
  __shared__ u32 part[8][64];
  const int t  = threadIdx.x;
  const int s  = t >> 6;
  const int k  = t & 63;
  const int gi = blockIdx.x * 64 + k;
  u32 count = ctr[0]; if (count > CAP) count = CAP;
  u64 my = (gi < (int)count) ? keys[gi] : 0ull;
  for (int j = t; j < CAP; j += 512)
    ks[j] = (j < (int)count) ? keys[j] : 0ull;
  __syncthreads();
  int rank = 0;
  { const ulonglong2* kp = reinterpret_cast<const ulonglong2*>(ks + s*1024);
    #pragma unroll 8
    for (int j = 0; j < 512; ++j){
      ulonglong2 kv = kp[j];
      rank += (kv.x > my) + (kv.y > my);
    } }
  part[s][k] = (u32)rank;
  __syncthreads();
  if (t < 64){
    int r = 0;
    #pragma unroll
    for (int ss = 0; ss < 8; ++ss) r += part[ss][k];
    bool sel = (gi < (int)count && r < PRE);
    int myv = 0x7FFFFFFF;
    if (sel && !((my >> 32) & 0x80000000ull)) myv = r;
    #pragma unroll
    for (int off = 32; off; off >>= 1){
      int o = __shfl_down(myv, off, 64);
      myv = (o < myv) ? o : myv;
    }
    if (k == 0 && myv != 0x7FFFFFFF) atomicMin((int*)(ctr + 4), myv);
    if (sel){
      u32 idx = ~(u32)my;
      float4 bv = make_float4(0.f,0.f,0.f,0.f);
      float area = 1.f;
      if (idx < NANCH){
        bv = boxes[idx];
        area = (bv.z - bv.x + 1.f) * (bv.w - bv.y + 1.f);
      }
      topB[r] = bv;
      topA[r] = area;
    }
  }
}

// ---------- K-mask (R32): ballot-built suppression words, transposed layout.
// One wave owns (word w, 64-row tile). Lane l keeps box j=w*64+l in REGISTERS (loaded once);
// per row i all lanes compute IoU(bi,bj); __ballot IS the 64-bit word. Stores coalesced to
// maskT[w*6000+i]. Same IoU expr as R31 (fp min/max/add commutative-exact, non-NaN inputs)
// -> identical booleans -> identical greedy kept set. ----------
__global__ __launch_bounds__(256) void k_mask(const float4* __restrict__ topB,
                                              u64* __restrict__ maskT){
  int wid  = (blockIdx.x * 256 + threadIdx.x) >> 6;   // global wave id
  int lane = threadIdx.x & 63;
  if (wid >= NW * 94) return;                         // 94 words x 94 row-tiles
  int w    = wid / 94;
  int rt   = wid - w * 94;
  int base = rt * 64;
  int j = w * 64 + lane;
  float4 bj = make_float4(0.f,0.f,0.f,0.f);
  if (j < PRE) bj = topB[j];
  float aj = (bj.z - bj.x + 1.f) * (bj.w - bj.y + 1.f);
  u64 myword = 0;
  for (int r = 0; r < 64; ++r){
    int i = base + r;
    float4 bi = make_float4(0.f,0.f,0.f,0.f);
    if (i < PRE) bi = topB[i];                        // same addr across wave -> broadcast
    float ai = (bi.z - bi.x + 1.f) * (bi.w - bi.y + 1.f);
    float xx1 = fmaxf(bi.x, bj.x);
    float yy1 = fmaxf(bi.y, bj.y);
    float xx2 = fminf(bi.z, bj.z);
    float yy2 = fminf(bi.w, bj.w);
    float iw = fmaxf(xx2 - xx1 + 1.f, 0.f);
    float ih = fmaxf(yy2 - yy1 + 1.f, 0.f);
    float inter = iw * ih;
    float iou = inter / (ai + aj - inter);
    bool sup = (j < PRE) && (iou > 0.7f);
    u64 word = __ballot(sup);
    if (lane == r) myword = word;
  }
  int i = base + lane;
  if (i < PRE) maskT[(long)w * 6000 + i] = myword;    // coalesced store
}

// ---------- helpers for k_nms4 ----------
__device__ __forceinline__ int findClear(u64 sa, u64 sb, int lane, int cur){
  const int cw = cur >> 6, cb = cur & 63;
  u64 ma = ~sa;
  if (lane < cw) ma = 0ull;
  else if (lane == cw) ma &= (~0ull) << cb;
  u64 bal = __ballot(ma != 0ull);
  if (bal){
    int wl = (int)__ffsll((unsigned long long)bal) - 1;
    u64 mw = (u64)__shfl((long long)ma, wl, 64);
    return wl * 64 + (int)__ffsll((unsigned long long)mw) - 1;
  }
  u64 mb = (lane < NW - 64) ? ~sb : 0ull;
  int w2 = 64 + lane;
  if (w2 < cw) mb = 0ull;
  else if (w2 == cw) mb &= (~0ull) << cb;
  u64 bal2 = __ballot(mb != 0ull);
  if (bal2){
    int wl = (int)__ffsll((unsigned long long)bal2) - 1;
    u64 mw = (u64)__shfl((long long)mb, wl, 64);
    return (64 + wl) * 64 + (int)__ffsll((unsigned long long)mw) - 1;
  }
  return -1;
}

// ---------- K-nms4 (R32): serial greedy scan + 2-candidate speculative row prefetch.
// The next keep is provably one of the PRE-OR state's clear bits {c1,c2,...}; issue c1/c2
// row loads BEFORE consuming row(i) so the likely-next row is in flight (hides L3/HBM
// latency, the R31 bottleneck: 300 dependent loads x ~1000cy = 144us). Miss -> fresh load.
// Kept set identical regardless of hit/miss. ----------
__global__ __launch_bounds__(64) void k_nms4(const float4* __restrict__ topB,
                                             const u32* __restrict__ ctr,
                                             const u64* __restrict__ maskT,
                                             float* __restrict__ out){
  __shared__ int kidx[POST];
  const int lane = threadIdx.x;
  int validN = (int)ctr[0];
  int finN   = (int)ctr[4];
  if (finN < validN) validN = finN;
  if (validN > PRE)  validN = PRE;

  auto initw = [&](int w)->u64 {
    int base = w * 64;
    if (base + 64 <= validN) return 0ull;
    if (base >= validN) return ~0ull;
    return (~0ull) << (validN - base);
  };
  u64 sa = initw(lane);
  u64 sb = (lane < NW - 64) ? initw(64 + lane) : ~0ull;

  int nk = 0;
  int i = findClear(sa, sb, lane, 0);
  u64 ra = 0, rb = 0;
  if (i >= 0){
    ra = maskT[(long)lane * 6000 + i];
    if (lane < NW - 64) rb = maskT[(long)(64 + lane) * 6000 + i];
  }
  while (i >= 0 && nk < POST){
    if (lane == 0) kidx[nk] = i;
    nk++;
    if (nk >= POST) break;
    int cur = i + 1;
    // candidates from PRE-OR state; issue their row loads (prefetch)
    int c1 = findClear(sa, sb, lane, cur);
    int c2 = (c1 >= 0) ? findClear(sa, sb, lane, c1 + 1) : -1;
    u64 p1a = 0, p1b = 0, p2a = 0, p2b = 0;
    if (c1 >= 0){
      p1a = maskT[(long)lane * 6000 + c1];
      if (lane < NW - 64) p1b = maskT[(long)(64 + lane) * 6000 + c1];
    }
    if (c2 >= 0){
      p2a = maskT[(long)lane * 6000 + c2];
      if (lane < NW - 64) p2b = maskT[(long)(64 + lane) * 6000 + c2];
    }
    // consume current row (the only wait in steady state)
    sa |= ra;
    if (lane < NW - 64) sb |= rb;
    i = findClear(sa, sb, lane, cur);
    if (i < 0) break;
    if (i == c1){ ra = p1a; rb = p1b; }
    else if (i == c2){ ra = p2a; rb = p2b; }
    else {
      ra = maskT[(long)lane * 6000 + i];
      rb = (lane < NW - 64) ? maskT[(long)(64 + lane) * 6000 + i] : 0ull;
    }
  }
  __syncthreads();
  for (int q = lane; q < 1500; q += 64){
    int r = q / 5, c = q - r*5;
    float v = 0.f;
    if (r < nk && c > 0){
      float4 bx = topB[kidx[r]];
      v = (c == 1) ? bx.x : (c == 2) ? bx.y : (c == 3) ? bx.z : bx.w;
    }
    out[q] = v;
  }
}

// ---------------- launch ----------------
extern "C" void kernel_launch(void* const* d_in, const int* in_sizes, int n_in,
                              void* d_out, int out_size, void* d_ws, size_t ws_size,
                              hipStream_t stream)
{
  const float* fm   = (const float*)d_in[0];
  const float* info = (const float*)d_in[1];
  const float* cw3  = (const float*)d_in[2];
  const float* cb3  = (const float*)d_in[3];
  const float* clw  = (const float*)d_in[4];
  const float* clb  = (const float*)d_in[5];
  const float* bbw  = (const float*)d_in[6];
  const float* bbb  = (const float*)d_in[7];
  float* out = (float*)d_out;

  char* base = (char*)d_ws;
  u32*   hist8g = (u32*)  (base + 0);          // 384*256 u32 = 393216 B
  u32*   hist2  = (u32*)  (base + 393216);     // 65536 u32  = 262144 B
  u32*   ctr    = (u32*)  (base + 655360);     // 16 u32: [0]=count [4]=finiteN
  float* Y      = (float*)(base + 655424);     // 12582912 B -> ends 13238336
  float* scores = (float*)(base + 13238336);   // 221184 B  -> ends 13459520
  float4* boxes = (float4*)(base + 13459520);  // 884736 B  -> ends 14344256
  u64*   keys   = (u64*)  (base + 14344256);   // 65536 B   -> ends 14409792
  float4* topB  = (float4*)(base + 14409792);  // 6000*16 = 96000 B -> ends 14505792
  float* topA   = (float*)(base + 14505792);   // 6000*4  = 24000 B -> ends 14529792
  unsigned short* Xih = (unsigned short*)(base + 14529792);  // 6623232 B -> ends 21153024
  unsigned short* Xil = (unsigned short*)(base + 21153024);  // 6623232 B -> ends 27776256
  unsigned short* Wh2 = (unsigned short*)(base + 27776256);  // 4718592 B -> ends 32494848
  unsigned short* Wl2 = (unsigned short*)(base + 32494848);  // 4718592 B -> ends 37213440
  float* Whd = (float*)(base + 37213440);      // 512*64 f32 -> ends 37344512
  // maskT (94*6000 u64 = 4512000 B) aliases the Xih region: Xih is dead after the conv
  // dispatches, and k_mask/k_nms4 run strictly after them in stream order.
  u64* maskT = (u64*)(base + 14529792);
  // total ws use: ~37.3 MB

  k_cvt   <<<1168, 256, 0, stream>>>(fm, cw3, clw, bbw, Xih, Xil, Wh2, Wl2, Whd, (u32*)base);
  k_conv3t<true,false>  <<<dim3(16, 16), 256, 0, stream>>>(Xih, Xil, Wh2, Wl2, cb3, Y);
  k_conv3t<false,true>  <<<dim3(16, 16), 256, 0, stream>>>(Xih, Xil, Wh2, Wl2, cb3, Y);
  k_head  <<<384, 256, 0, stream>>>(Y, Whd, clb, bbb, info, scores, boxes, hist8g);
  k_sel   <<<1,  1024, 0, stream>>>(hist8g, hist2, scores, ctr, keys);
  k_rank  <<<128, 512, 0, stream>>>(keys, ctr, boxes, topB, topA);
  k_mask  <<<(NW*94*64 + 255)/256, 256, 0, stream>>>(topB, maskT);
  k_nms4  <<<1, 64, 0, stream>>>(topB, ctr, maskT, out);
}

// Round 11
// 409.236 us; speedup vs baseline: 1.3646x; 1.3646x over previous
//
#include <hip/hip_runtime.h>
#include <stdint.h>

typedef unsigned int u32;
typedef unsigned long long u64;
typedef __attribute__((ext_vector_type(8))) short v8s;   // 8 bf16 = 4 VGPR (MFMA A/B frag)
typedef __attribute__((ext_vector_type(4))) float v4f;   // MFMA C/D frag

#define HH 64
#define WW 96
#define HW 6144
#define CC 512
#define NANCH 55296
#define PRE 6000
#define POST 300
#define CAP 8192
#define PW 98
#define PH 66
#define ICPAD 40
#define NHB 384          // k_head blocks (hist8g partials)

__device__ __constant__ float c_aw[9] = {184.f,368.f,736.f,128.f,256.f,512.f,88.f,176.f,352.f};
__device__ __constant__ float c_ah[9] = {96.f,192.f,384.f,128.f,256.f,512.f,176.f,352.f,704.f};

__device__ __forceinline__ unsigned short bf16_rne(float x){
  u32 u = __float_as_uint(x);
  return (unsigned short)((u + 0x7FFFu + ((u >> 16) & 1u)) >> 16);
}
__device__ __forceinline__ u32 sortkey(float s){
  u32 u = __float_as_uint(s);
  return u ^ ((u & 0x80000000u) ? 0xFFFFFFFFu : 0x80000000u);
}

// ---------- K0: merged convert + zeroing — R29: u64-packed bf16 hi/lo stores ----------
__global__ __launch_bounds__(256) void k_cvt(const float* __restrict__ X, const float* __restrict__ Wt,
                                             const float* __restrict__ cw, const float* __restrict__ bw,
                                             unsigned short* __restrict__ Xih, unsigned short* __restrict__ Xil,
                                             unsigned short* __restrict__ Wh2, unsigned short* __restrict__ Wl2,
                                             float* __restrict__ Whd, u32* __restrict__ zero_region){
  __shared__ float Ls[64][97];
  __shared__ float Ws[4608];
  const int b = blockIdx.x, tid = threadIdx.x;
  { int gid = b*256 + tid;
    if (gid < 163856) zero_region[gid] = 0u; }   // hist8g (98304) + hist2 (65536) + ctr (16)
  if (b < 528){
    const int rp  = b % 66;
    const int ic0 = (b / 66) * 64;
    const bool zrow = (rp == 0 || rp == PH-1);
    if (!zrow){
      int r = rp - 1;
      for (int i = tid; i < 6144; i += 256){
        int ii = i / 96, c = i - ii*96;
        Ls[ii][c] = X[(ic0+ii)*HW + r*WW + c];
      }
    }
    __syncthreads();
    for (int idx = tid; idx < 98*16; idx += 256){
      int cp = idx >> 4, g = idx & 15;
      int icl0 = g*4;
      u64 hv = 0, lv = 0;
      #pragma unroll
      for (int u = 0; u < 4; ++u){
        float x = 0.f;
        if (!zrow && cp >= 1 && cp <= 96) x = Ls[icl0+u][cp-1];
        unsigned short h = bf16_rne(x);
        float hf = __uint_as_float(((u32)h) << 16);
        unsigned short l = bf16_rne(x - hf);
        hv |= ((u64)h) << (16*u);
        lv |= ((u64)l) << (16*u);
      }
      long o = ((long)(rp*PW + cp) << 9) + ic0 + icl0;
      *reinterpret_cast<u64*>(Xih + o) = hv;
      *reinterpret_cast<u64*>(Xil + o) = lv;
    }
  } else if (b < 1040){
    const int oc = b - 528;
    for (int i = tid; i < 4608; i += 256) Ws[i] = Wt[oc*4608 + i];
    __syncthreads();
    for (int idx = tid; idx < 9*128; idx += 256){
      int tap = idx >> 7, g = idx & 127;
      int icb = g*4;
      u64 hv = 0, lv = 0;
      #pragma unroll
      for (int u = 0; u < 4; ++u){
        float x = Ws[(icb+u)*9 + tap];
        unsigned short h = bf16_rne(x);
        float hf = __uint_as_float(((u32)h) << 16);
        unsigned short l = bf16_rne(x - hf);
        hv |= ((u64)h) << (16*u);
        lv |= ((u64)l) << (16*u);
      }
      long o = ((long)(tap*512 + oc) << 9) + icb;
      *reinterpret_cast<u64*>(Wh2 + o) = hv;
      *reinterpret_cast<u64*>(Wl2 + o) = lv;
    }
  } else {
    // head-weight transpose: Whd[gc*64 + o]
    int idx = (b - 1040)*256 + tid;
    int o  = idx >> 9;
    int gc = idx & 511;
    float v = 0.f;
    if (o < 18) v = cw[o*512 + gc];
    else if (o < 54) v = bw[(o-18)*512 + gc];
    Whd[gc*64 + o] = v;
  }
}

// ---------- K1: MFMA conv, LDS-staged + register double-buffer (R28-proven 116.5µs, merged back) ----------
// R33: re-merged from the R29 K-split (visibility no longer needed; reclaims Y round-trip).
__global__ __launch_bounds__(256, 1) void k_conv3(
    const unsigned short* __restrict__ Xih, const unsigned short* __restrict__ Xil,
    const unsigned short* __restrict__ Wh2, const unsigned short* __restrict__ Wl2,
    const float* __restrict__ Bc, float* __restrict__ Y)
{
  __shared__ __attribute__((aligned(16))) unsigned short Ah[6*98*ICPAD];
  __shared__ __attribute__((aligned(16))) unsigned short Al[6*98*ICPAD];
  __shared__ __attribute__((aligned(16))) unsigned short Bh[9*32*ICPAD];
  __shared__ __attribute__((aligned(16))) unsigned short Bl[9*32*ICPAD];
  const int tid  = threadIdx.x;
  const int w    = tid >> 6;
  const int lane = tid & 63;
  const int lm   = lane & 15;
  const int q    = lane >> 4;
  const int y0   = blockIdx.x * 4;
  const int oc0  = blockIdx.y * 32;

  v4f acc[6][2];
  #pragma unroll
  for (int t = 0; t < 6; ++t)
    #pragma unroll
    for (int n = 0; n < 2; ++n)
      acc[t][n] = (v4f){0.f,0.f,0.f,0.f};

  u64 ra[19][2], rb[9][2];
  auto loadSlab = [&](int icg){
    #pragma unroll
    for (int n = 0; n < 19; ++n){
      int it = tid + 256*n;
      if (it < 4704){
        int i4 = it & 7, rc = it >> 3;
        int c = rc % 98, r = rc / 98;
        long src = ((long)((y0 + r)*PW + c) << 9) + icg*32 + i4*4;
        ra[n][0] = *reinterpret_cast<const u64*>(Xih + src);
        ra[n][1] = *reinterpret_cast<const u64*>(Xil + src);
      }
    }
    #pragma unroll
    for (int n = 0; n < 9; ++n){
      int it = tid + 256*n;
      if (it < 2304){
        int i4 = it & 7, to = it >> 3;
        int oc = to & 31, tap = to >> 5;
        long src = ((long)(tap*512 + oc0 + oc) << 9) + icg*32 + i4*4;
        rb[n][0] = *reinterpret_cast<const u64*>(Wh2 + src);
        rb[n][1] = *reinterpret_cast<const u64*>(Wl2 + src);
      }
    }
  };
  auto storeSlab = [&](){
    #pragma unroll
    for (int n = 0; n < 19; ++n){
      int it = tid + 256*n;
      if (it < 4704){
        int i4 = it & 7, rc = it >> 3;
        int dst = rc*ICPAD + i4*4;
        *reinterpret_cast<u64*>(Ah + dst) = ra[n][0];
        *reinterpret_cast<u64*>(Al + dst) = ra[n][1];
      }
    }
    #pragma unroll
    for (int n = 0; n < 9; ++n){
      int it = tid + 256*n;
      if (it < 2304){
        int i4 = it & 7, to = it >> 3;
        int dst = to*ICPAD + i4*4;
        *reinterpret_cast<u64*>(Bh + dst) = rb[n][0];
        *reinterpret_cast<u64*>(Bl + dst) = rb[n][1];
      }
    }
  };

  loadSlab(0);
  for (int icg = 0; icg < 16; ++icg){
    __syncthreads();
    storeSlab();
    __syncthreads();
    if (icg < 15) loadSlab(icg + 1);
    #pragma unroll
    for (int tap = 0; tap < 9; ++tap){
      const int dy = tap / 3, dx = tap - dy*3;
      v8s ah[6], al[6], bh[2], bl[2];
      #pragma unroll
      for (int t = 0; t < 6; ++t){
        int a = ((w + dy)*98 + 16*t + lm + dx)*ICPAD + q*8;
        ah[t] = *reinterpret_cast<const v8s*>(Ah + a);
        al[t] = *reinterpret_cast<const v8s*>(Al + a);
      }
      #pragma unroll
      for (int n = 0; n < 2; ++n){
        int a = (tap*32 + n*16 + lm)*ICPAD + q*8;
        bh[n] = *reinterpret_cast<const v8s*>(Bh + a);
        bl[n] = *reinterpret_cast<const v8s*>(Bl + a);
      }
      #pragma unroll
      for (int t = 0; t < 6; ++t)
        #pragma unroll
        for (int n = 0; n < 2; ++n){
          acc[t][n] = __builtin_amdgcn_mfma_f32_16x16x32_bf16(al[t], bl[n], acc[t][n], 0, 0, 0);
          acc[t][n] = __builtin_amdgcn_mfma_f32_16x16x32_bf16(al[t], bh[n], acc[t][n], 0, 0, 0);
          acc[t][n] = __builtin_amdgcn_mfma_f32_16x16x32_bf16(ah[t], bl[n], acc[t][n], 0, 0, 0);
          acc[t][n] = __builtin_amdgcn_mfma_f32_16x16x32_bf16(ah[t], bh[n], acc[t][n], 0, 0, 0);
        }
    }
  }
  const int yrow = y0 + w;
  #pragma unroll
  for (int n = 0; n < 2; ++n){
    int oc = oc0 + n*16 + lm;
    float b = Bc[oc];
    #pragma unroll
    for (int t = 0; t < 6; ++t){
      float4 v;
      v.x = fmaxf(acc[t][n].x + b, 0.f);
      v.y = fmaxf(acc[t][n].y + b, 0.f);
      v.z = fmaxf(acc[t][n].z + b, 0.f);
      v.w = fmaxf(acc[t][n].w + b, 0.f);
      *reinterpret_cast<float4*>(Y + (long)oc*HW + yrow*WW + 16*t + q*4) = v;
    }
  }
}

// ---------------- K2: 1x1 heads + softmax + box decode (R27/R28 proven) ----------------
__global__ __launch_bounds__(256) void k_head(
    const float* __restrict__ Y, const float* __restrict__ Whd,
    const float* __restrict__ cb, const float* __restrict__ bb,
    const float* __restrict__ info,
    float* __restrict__ scores, float4* __restrict__ boxes, u32* __restrict__ hist8g)
{
  __shared__ float Ys[1024];
  __shared__ float Wsh[4096];   // transposed: Wsh[c*64 + (o&15)*4 + (o>>4)] = W[c][o]
  __shared__ u32 lh[256];
  const int tid = threadIdx.x;
  const int p0  = blockIdx.x * 16;
  const int po  = tid & 15;
  const int oj  = tid >> 4;
  lh[tid] = 0u;
  float accM[4], accC[4];
  #pragma unroll
  for (int k = 0; k < 4; ++k){ accM[k] = 0.f; accC[k] = 0.f; }

  for (int c0 = 0; c0 < CC; c0 += 64){
    __syncthreads();
    for (int i = tid; i < 1024; i += 256){
      int c = i >> 4, p = i & 15;
      Ys[i] = Y[(c0 + c) * HW + p0 + p];
    }
    for (int i = tid; i < 4096; i += 256){
      int c = i >> 6, o = i & 63;
      Wsh[c*64 + (o & 15)*4 + (o >> 4)] = Whd[(c0 + c)*64 + o];
    }
    __syncthreads();
    #pragma unroll 4
    for (int c = 0; c < 64; ++c){
      float xa = Ys[c*16 + po];
      float4 wv = *reinterpret_cast<const float4*>(Wsh + c*64 + oj*4);
      accC[0] = __fmaf_rn(xa, wv.x, accC[0]);
      accC[1] = __fmaf_rn(xa, wv.y, accC[1]);
      accC[2] = __fmaf_rn(xa, wv.z, accC[2]);
      accC[3] = __fmaf_rn(xa, wv.w, accC[3]);
    }
    #pragma unroll
    for (int k = 0; k < 4; ++k){ accM[k] += accC[k]; accC[k] = 0.f; }
  }
  __syncthreads();
  #pragma unroll
  for (int k = 0; k < 4; ++k){
    int o = oj + 16*k;
    float bias = (o < 18) ? cb[o] : ((o < 54) ? bb[o - 18] : 0.f);
    Ys[po*64 + o] = accM[k] + bias;
  }
  __syncthreads();
  float imH = info[0], imW = info[1], imS = info[2];
  for (int it = tid; it < 144; it += 256){
    int pl = it / 9;
    int a  = it - pl*9;
    const float* L = Ys + pl*64;
    float l0 = L[a], l1 = L[9 + a];
    float mx = fmaxf(l0, l1);
    float e0 = expf(l0 - mx), e1 = expf(l1 - mx);
    float sc = e1 / (e0 + e1);
    float d0 = L[18 + a*4 + 0], d1 = L[18 + a*4 + 1];
    float d2 = L[18 + a*4 + 2], d3 = L[18 + a*4 + 3];
    int pos = p0 + pl;
    int yy = pos / 96;
    int xx = pos - yy * 96;
    float aw = c_aw[a], ah = c_ah[a];
    float acx = (float)(xx * 16 + 8);
    float acy = (float)(yy * 16 + 8);
    float cx = __fadd_rn(__fmul_rn(d0, aw), acx);
    float cy = __fadd_rn(__fmul_rn(d1, ah), acy);
    float pw = __fmul_rn(expf(d2), aw);
    float ph = __fmul_rn(expf(d3), ah);
    float hx = __fmul_rn(0.5f, pw);
    float hy = __fmul_rn(0.5f, ph);
    float x1 = fminf(fmaxf(__fadd_rn(cx, -hx), 0.f), imW - 1.f);
    float y1 = fminf(fmaxf(__fadd_rn(cy, -hy), 0.f), imH - 1.f);
    float x2 = fminf(fmaxf(__fadd_rn(cx,  hx), 0.f), imW - 1.f);
    float y2 = fminf(fmaxf(__fadd_rn(cy,  hy), 0.f), imH - 1.f);
    float ms = 16.f * imS;
    bool keep = ((x2 - x1 + 1.f) >= ms) && ((y2 - y1 + 1.f) >= ms);
    int g = pos * 9 + a;
    float val = keep ? sc : -__builtin_inff();
    scores[g] = val;
    boxes[g]  = make_float4(x1, y1, x2, y2);
    atomicAdd(&lh[sortkey(val) >> 24], 1u);   // LDS atomic, block-private
  }
  __syncthreads();
  hist8g[blockIdx.x*256 + tid] = lh[tid];     // plain coalesced store
}

// ---------- K3: fused selection — R27 3-level exact radix select (proven) ----------
__global__ __launch_bounds__(1024) void k_sel(const u32* __restrict__ hist8g, u32* __restrict__ hist2,
                                              const float* __restrict__ scores,
                                              u32* __restrict__ ctr, u64* __restrict__ keys){
  __shared__ u32 cs[1024];
  __shared__ u32 bs[64];
  __shared__ u32 h8[256];
  __shared__ u32 lh2[256];
  __shared__ int selg;
  __shared__ u32 afterv, T16s, aboves, K32s, B8s, above8s;
  const int t = threadIdx.x;
  const int b0 = t * 64;

  // ---- L1: merge per-block 256-bin partials ----
  { int g = t >> 8, bin = t & 255;
    u32 s = 0;
    for (int b = g; b < NHB; b += 4) s += hist8g[b*256 + bin];
    cs[t] = s; }
  __syncthreads();
  if (t < 256){
    h8[t] = cs[t] + cs[256 + t] + cs[512 + t] + cs[768 + t];
    lh2[t] = 0u;
  }
  __syncthreads();
  if (t == 0){
    u32 acc = 0;
    for (int bin = 255; bin >= 0; --bin){
      acc += h8[bin];
      if (acc >= 6000u){ B8s = (u32)bin; above8s = acc - h8[bin]; break; }
    }
  }
  __syncthreads();

  // ---- L2: 256-bin scan over next 8 bits among keys with top8 == B8 ----
  { u32 b8 = B8s;
    const float4* s4 = reinterpret_cast<const float4*>(scores);
    for (int i = t; i < NANCH/4; i += 1024){
      float4 v = s4[i];
      u32 k0 = sortkey(v.x), k1 = sortkey(v.y), k2 = sortkey(v.z), k3 = sortkey(v.w);
      if ((k0 >> 24) == b8) atomicAdd(&lh2[(k0 >> 16) & 0xFFu], 1u);
      if ((k1 >> 24) == b8) atomicAdd(&lh2[(k1 >> 16) & 0xFFu], 1u);
      if ((k2 >> 24) == b8) atomicAdd(&lh2[(k2 >> 16) & 0xFFu], 1u);
      if ((k3 >> 24) == b8) atomicAdd(&lh2[(k3 >> 16) & 0xFFu], 1u);
    } }
  __syncthreads();
  if (t == 0){
    u32 acc = above8s;
    for (int bin = 255; bin >= 0; --bin){
      acc += lh2[bin];
      if (acc >= 6000u){ T16s = (B8s << 8) | (u32)bin; aboves = acc - lh2[bin]; break; }
    }
  }
  __syncthreads();

  // ---- L3: hist2 over low 16 bits among keys with top16 == T16s ----
  { u32 pfx = T16s;
    const float4* s4 = reinterpret_cast<const float4*>(scores);
    for (int i = t; i < NANCH/4; i += 1024){
      float4 v = s4[i];
      u32 k0 = sortkey(v.x), k1 = sortkey(v.y), k2 = sortkey(v.z), k3 = sortkey(v.w);
      if ((k0 >> 16) == pfx) atomicAdd(&hist2[k0 & 0xFFFFu], 1u);
      if ((k1 >> 16) == pfx) atomicAdd(&hist2[k1 & 0xFFFFu], 1u);
      if ((k2 >> 16) == pfx) atomicAdd(&hist2[k2 & 0xFFFFu], 1u);
      if ((k3 >> 16) == pfx) atomicAdd(&hist2[k3 & 0xFFFFu], 1u);
    } }
  __threadfence();
  __syncthreads();

  if (t == 0) selg = -1;
  __syncthreads();
  const u32 target = 6000u - aboves;
  { u32 s = 0;
    for (int i = 0; i < 64; ++i) s += hist2[b0 + i];
    cs[t] = s; }
  __syncthreads();
  for (int off = 1; off < 1024; off <<= 1){
    u32 v = cs[t];
    u32 ad = (t + off < 1024) ? cs[t + off] : 0u;
    __syncthreads();
    cs[t] = v + ad;
    __syncthreads();
  }
  { u32 here  = cs[t];
    u32 after = (t < 1023) ? cs[t + 1] : 0u;
    if (here >= target && after < target){ selg = t; afterv = after; } }
  __syncthreads();
  { int g = selg;
    if (g >= 0 && t < 64) bs[t] = hist2[g*64 + t];
    __syncthreads();
    if (t == 0){
      if (g < 0) K32s = (T16s << 16);
      else {
        u32 acc = afterv;
        for (int b = 63; b >= 0; --b){
          u32 h = bs[b];
          acc += h;
          if (acc >= target){ K32s = (T16s << 16) | (u32)(g*64 + b); break; }
        }
      }
      ctr[4] = 6000u;
    } }
  __syncthreads();

  // ---- compact: ballot-aggregated counter ----
  { u32 K = K32s;
    const int lane = t & 63;
    const float4* s4 = reinterpret_cast<const float4*>(scores);
    for (int i = t; i < NANCH/4; i += 1024){
      float4 v = s4[i];
      u32 kk[4] = {sortkey(v.x), sortkey(v.y), sortkey(v.z), sortkey(v.w)};
      u64 m[4];
      #pragma unroll
      for (int u = 0; u < 4; ++u) m[u] = __ballot(kk[u] >= K);
      u32 tot = (u32)(__popcll(m[0]) + __popcll(m[1]) + __popcll(m[2]) + __popcll(m[3]));
      if (tot){
        u32 base = 0;
        if (lane == 0) base = atomicAdd(&ctr[0], tot);
        base = (u32)__shfl((int)base, 0, 64);
        u64 below = ((u64)1 << lane) - 1;
        u32 off = 0;
        #pragma unroll
        for (int u = 0; u < 4; ++u){
          if (kk[u] >= K){
            u32 pos = base + off + (u32)__popcll(m[u] & below);
            if (pos < CAP) keys[pos] = ((u64)kk[u] << 32) | (u64)(u32)(~(u32)(i*4 + u));
          }
          off += (u32)__popcll(m[u]);
        }
      }
    } }
}

// ---------------- K-rank — R27: block-reduced atomicMin (proven) ----------------
__global__ __launch_bounds__(512) void k_rank(const u64* __restrict__ keys, u32* __restrict__ ctr,
                                              const float4* __restrict__ boxes,
                                              float4* __restrict__ topB, float* __restrict__ topA){
  __shared__ u64 ks[CAP];        // 64 KB
  __shared__ u32 part[8][64];
  const int t  = threadIdx.x;
  const int s  = t >> 6;
  const int k  = t & 63;
  const int gi = blockIdx.x * 64 + k;
  u32 count = ctr[0]; if (count > CAP) count = CAP;
  u64 my = (gi < (int)count) ? keys[gi] : 0ull;
  for (int j = t; j < CAP; j += 512)
    ks[j] = (j < (int)count) ? keys[j] : 0ull;
  __syncthreads();
  int rank = 0;
  { const ulonglong2* kp = reinterpret_cast<const ulonglong2*>(ks + s*1024);
    #pragma unroll 8
    for (int j = 0; j < 512; ++j){
      ulonglong2 kv = kp[j];
      rank += (kv.x > my) + (kv.y > my);
    } }
  part[s][k] = (u32)rank;
  __syncthreads();
  if (t < 64){
    int r = 0;
    #pragma unroll
    for (int ss = 0; ss < 8; ++ss) r += part[ss][k];
    bool sel = (gi < (int)count && r < PRE);
    int myv = 0x7FFFFFFF;
    if (sel && !((my >> 32) & 0x80000000ull)) myv = r;
    #pragma unroll
    for (int off = 32; off; off >>= 1){
      int o = __shfl_down(myv, off, 64);
      myv = (o < myv) ? o : myv;
    }
    if (k == 0 && myv != 0x7FFFFFFF) atomicMin((int*)(ctr + 4), myv);
    if (sel){
      u32 idx = ~(u32)my;
      float4 bv = make_float4(0.f,0.f,0.f,0.f);
      float area = 1.f;
      if (idx < NANCH){
        bv = boxes[idx];
        area = (bv.z - bv.x + 1.f) * (bv.w - bv.y + 1.f);
      }
      topB[r] = bv;
      topA[r] = area;
    }
  }
}

// ---------- K5: chunked exact NMS — R30-proven (91.4µs): 4-wave Phase A + wave-0 Phase B,
// LDS box-broadcast in Phase B, area recompute in Phase A. R31/R32 bitmatrix variants both
// regressed (dependent global row loads ~1000cy x 300 keeps); this is the structural floor. ----------
__global__ __launch_bounds__(256) void k_nms3(const float4* __restrict__ topB,
                                              const u32* __restrict__ ctr, float* __restrict__ out){
  __shared__ float4 kb[POST];
  __shared__ float4 bx2[64];
  __shared__ u64    am[4];
  __shared__ int    nkS;
  const int tid  = threadIdx.x;
  const int wv   = tid >> 6;
  const int lane = tid & 63;
  int validN = (int)ctr[0];
  int finN   = (int)ctr[4];
  if (finN < validN) validN = finN;
  if (validN > PRE)  validN = PRE;
  if (tid == 0) nkS = 0;
  __syncthreads();

  float4 bnx = make_float4(0.f,0.f,0.f,0.f);
  if (lane < validN) bnx = topB[lane];

  for (int base = 0; base < validN; base += 64){
    int nk = nkS;
    if (nk >= POST) break;
    int c = base + lane;
    bool alive = (c < validN);
    float4 b = bnx;
    float ar = alive ? (b.z - b.x + 1.f) * (b.w - b.y + 1.f) : 1.f;
    if (wv == 0) bx2[lane] = b;          // stage chunk boxes for Phase B broadcast
    { int cn = base + 64 + lane;
      if (cn < validN) bnx = topB[cn]; }
    int j = wv;
    for (; j + 28 < nk; j += 32){
      float4 kx[8];
      #pragma unroll
      for (int u = 0; u < 8; ++u) kx[u] = kb[j + 4*u];
      #pragma unroll
      for (int u = 0; u < 8; ++u){
        float kar = (kx[u].z - kx[u].x + 1.f) * (kx[u].w - kx[u].y + 1.f);
        float xx1 = fmaxf(kx[u].x, b.x);
        float yy1 = fmaxf(kx[u].y, b.y);
        float xx2 = fminf(kx[u].z, b.z);
        float yy2 = fminf(kx[u].w, b.w);
        float iw = fmaxf(xx2 - xx1 + 1.f, 0.f);
        float ih = fmaxf(yy2 - yy1 + 1.f, 0.f);
        float inter = iw * ih;
        float iou = inter / (kar + ar - inter);
        if (iou > 0.7f) alive = false;
      }
    }
    for (; j < nk; j += 4){
      float4 kbx = kb[j];
      float kar = (kbx.z - kbx.x + 1.f) * (kbx.w - kbx.y + 1.f);
      float xx1 = fmaxf(kbx.x, b.x);
      float yy1 = fmaxf(kbx.y, b.y);
      float xx2 = fminf(kbx.z, b.z);
      float yy2 = fminf(kbx.w, b.w);
      float iw = fmaxf(xx2 - xx1 + 1.f, 0.f);
      float ih = fmaxf(yy2 - yy1 + 1.f, 0.f);
      float inter = iw * ih;
      float iou = inter / (kar + ar - inter);
      if (iou > 0.7f) alive = false;
    }
    { u64 bal = __ballot(alive);
      if (lane == 0) am[wv] = bal; }
    __syncthreads();
    if (wv == 0){
      u64 comb = am[0] & am[1] & am[2] & am[3];
      alive = ((comb >> lane) & 1ull) != 0ull;
      int nkl = nk;
      while (nkl < POST){
        u64 bal = __ballot(alive);
        if (!bal) break;
        int L = (int)__ffsll((unsigned long long)bal) - 1;
        float4 pb = bx2[L];              // broadcast LDS read
        float pa = (pb.z - pb.x + 1.f) * (pb.w - pb.y + 1.f);
        if (lane == 0) kb[nkl] = pb;
        nkl++;
        if (lane == L) alive = false;
        if (alive){
          float xx1 = fmaxf(pb.x, b.x);
          float yy1 = fmaxf(pb.y, b.y);
          float xx2 = fminf(pb.z, b.z);
          float yy2 = fminf(pb.w, b.w);
          float iw = fmaxf(xx2 - xx1 + 1.f, 0.f);
          float ih = fmaxf(yy2 - yy1 + 1.f, 0.f);
          float inter = iw * ih;
          float iou = inter / (pa + ar - inter);
          if (iou > 0.7f) alive = false;
        }
      }
      if (lane == 0) nkS = nkl;
    }
    __syncthreads();
  }
  int nk = nkS;
  for (int q = tid; q < 1500; q += 256){
    int r = q / 5, c = q - r*5;
    float v = 0.f;
    if (r < nk && c > 0){
      float4 bx = kb[r];
      v = (c == 1) ? bx.x : (c == 2) ? bx.y : (c == 3) ? bx.z : bx.w;
    }
    out[q] = v;
  }
}

// ---------------- launch ----------------
extern "C" void kernel_launch(void* const* d_in, const int* in_sizes, int n_in,
                              void* d_out, int out_size, void* d_ws, size_t ws_size,
                              hipStream_t stream)
{
  const float* fm   = (const float*)d_in[0];
  const float* info = (const float*)d_in[1];
  const float* cw3  = (const float*)d_in[2];
  const float* cb3  = (const float*)d_in[3];
  const float* clw  = (const float*)d_in[4];
  const float* clb  = (const float*)d_in[5];
  const float* bbw  = (const float*)d_in[6];
  const float* bbb  = (const float*)d_in[7];
  float* out = (float*)d_out;

  char* base = (char*)d_ws;
  u32*   hist8g = (u32*)  (base + 0);          // 384*256 u32 = 393216 B
  u32*   hist2  = (u32*)  (base + 393216);     // 65536 u32  = 262144 B
  u32*   ctr    = (u32*)  (base + 655360);     // 16 u32: [0]=count [4]=finiteN
  float* Y      = (float*)(base + 655424);     // 12582912 B -> ends 13238336
  float* scores = (float*)(base + 13238336);   // 221184 B  -> ends 13459520
  float4* boxes = (float4*)(base + 13459520);  // 884736 B  -> ends 14344256
  u64*   keys   = (u64*)  (base + 14344256);   // 65536 B   -> ends 14409792
  float4* topB  = (float4*)(base + 14409792);  // 6000*16 = 96000 B -> ends 14505792
  float* topA   = (float*)(base + 14505792);   // 6000*4  = 24000 B -> ends 14529792
  unsigned short* Xih = (unsigned short*)(base + 14529792);  // 6623232 B -> ends 21153024
  unsigned short* Xil = (unsigned short*)(base + 21153024);  // 6623232 B -> ends 27776256
  unsigned short* Wh2 = (unsigned short*)(base + 27776256);  // 4718592 B -> ends 32494848
  unsigned short* Wl2 = (unsigned short*)(base + 32494848);  // 4718592 B -> ends 37213440
  float* Whd = (float*)(base + 37213440);      // 512*64 f32 -> ends 37344512
  // total ws use: ~37.3 MB

  k_cvt   <<<1168, 256, 0, stream>>>(fm, cw3, clw, bbw, Xih, Xil, Wh2, Wl2, Whd, (u32*)base);
  k_conv3 <<<dim3(16, 16), 256, 0, stream>>>(Xih, Xil, Wh2, Wl2, cb3, Y);
  k_head  <<<384, 256, 0, stream>>>(Y, Whd, clb, bbb, info, scores, boxes, hist8g);
  k_sel   <<<1,  1024, 0, stream>>>(hist8g, hist2, scores, ctr, keys);
  k_rank  <<<128, 512, 0, stream>>>(keys, ctr, boxes, topB, topA);
  k_nms3  <<<1,   256, 0, stream>>>(topB, ctr, out);
}

// Round 12
// 359.205 us; speedup vs baseline: 1.5547x; 1.1393x over previous
//
#include <hip/hip_runtime.h>
#include <stdint.h>

typedef unsigned int u32;
typedef unsigned long long u64;
typedef __attribute__((ext_vector_type(8))) short v8s;   // 8 bf16 = 4 VGPR (MFMA A/B frag)
typedef __attribute__((ext_vector_type(4))) float v4f;   // MFMA C/D frag

#define HH 64
#define WW 96
#define HW 6144
#define CC 512
#define NANCH 55296
#define PRE 6000
#define POST 300
#define CAP 8192
#define PW 98
#define PH 66
#define ICPAD 40
#define NHB 384          // k_head blocks (hist8g partials)

__device__ __constant__ float c_aw[9] = {184.f,368.f,736.f,128.f,256.f,512.f,88.f,176.f,352.f};
__device__ __constant__ float c_ah[9] = {96.f,192.f,384.f,128.f,256.f,512.f,176.f,352.f,704.f};

__device__ __forceinline__ unsigned short bf16_rne(float x){
  u32 u = __float_as_uint(x);
  return (unsigned short)((u + 0x7FFFu + ((u >> 16) & 1u)) >> 16);
}
__device__ __forceinline__ u32 sortkey(float s){
  u32 u = __float_as_uint(s);
  return u ^ ((u & 0x80000000u) ? 0xFFFFFFFFu : 0x80000000u);
}

// ---------- K0: merged convert + zeroing — R29: u64-packed bf16 hi/lo stores ----------
__global__ __launch_bounds__(256) void k_cvt(const float* __restrict__ X, const float* __restrict__ Wt,
                                             const float* __restrict__ cw, const float* __restrict__ bw,
                                             unsigned short* __restrict__ Xih, unsigned short* __restrict__ Xil,
                                             unsigned short* __restrict__ Wh2, unsigned short* __restrict__ Wl2,
                                             float* __restrict__ Whd, u32* __restrict__ zero_region){
  __shared__ float Ls[64][97];
  __shared__ float Ws[4608];
  const int b = blockIdx.x, tid = threadIdx.x;
  { int gid = b*256 + tid;
    if (gid < 163856) zero_region[gid] = 0u; }   // hist8g (98304) + hist2 (65536) + ctr (16)
  if (b < 528){
    const int rp  = b % 66;
    const int ic0 = (b / 66) * 64;
    const bool zrow = (rp == 0 || rp == PH-1);
    if (!zrow){
      int r = rp - 1;
      for (int i = tid; i < 6144; i += 256){
        int ii = i / 96, c = i - ii*96;
        Ls[ii][c] = X[(ic0+ii)*HW + r*WW + c];
      }
    }
    __syncthreads();
    for (int idx = tid; idx < 98*16; idx += 256){
      int cp = idx >> 4, g = idx & 15;
      int icl0 = g*4;
      u64 hv = 0, lv = 0;
      #pragma unroll
      for (int u = 0; u < 4; ++u){
        float x = 0.f;
        if (!zrow && cp >= 1 && cp <= 96) x = Ls[icl0+u][cp-1];
        unsigned short h = bf16_rne(x);
        float hf = __uint_as_float(((u32)h) << 16);
        unsigned short l = bf16_rne(x - hf);
        hv |= ((u64)h) << (16*u);
        lv |= ((u64)l) << (16*u);
      }
      long o = ((long)(rp*PW + cp) << 9) + ic0 + icl0;
      *reinterpret_cast<u64*>(Xih + o) = hv;
      *reinterpret_cast<u64*>(Xil + o) = lv;
    }
  } else if (b < 1040){
    const int oc = b - 528;
    for (int i = tid; i < 4608; i += 256) Ws[i] = Wt[oc*4608 + i];
    __syncthreads();
    for (int idx = tid; idx < 9*128; idx += 256){
      int tap = idx >> 7, g = idx & 127;
      int icb = g*4;
      u64 hv = 0, lv = 0;
      #pragma unroll
      for (int u = 0; u < 4; ++u){
        float x = Ws[(icb+u)*9 + tap];
        unsigned short h = bf16_rne(x);
        float hf = __uint_as_float(((u32)h) << 16);
        unsigned short l = bf16_rne(x - hf);
        hv |= ((u64)h) << (16*u);
        lv |= ((u64)l) << (16*u);
      }
      long o = ((long)(tap*512 + oc) << 9) + icb;
      *reinterpret_cast<u64*>(Wh2 + o) = hv;
      *reinterpret_cast<u64*>(Wl2 + o) = lv;
    }
  } else {
    // head-weight transpose: Whd[gc*64 + o]
    int idx = (b - 1040)*256 + tid;
    int o  = idx >> 9;
    int gc = idx & 511;
    float v = 0.f;
    if (o < 18) v = cw[o*512 + gc];
    else if (o < 54) v = bw[(o-18)*512 + gc];
    Whd[gc*64 + o] = v;
  }
}

// ---------- K1: MFMA conv, LDS-staged + register double-buffer (R28-proven 116.5µs) ----------
__global__ __launch_bounds__(256, 1) void k_conv3(
    const unsigned short* __restrict__ Xih, const unsigned short* __restrict__ Xil,
    const unsigned short* __restrict__ Wh2, const unsigned short* __restrict__ Wl2,
    const float* __restrict__ Bc, float* __restrict__ Y)
{
  __shared__ __attribute__((aligned(16))) unsigned short Ah[6*98*ICPAD];
  __shared__ __attribute__((aligned(16))) unsigned short Al[6*98*ICPAD];
  __shared__ __attribute__((aligned(16))) unsigned short Bh[9*32*ICPAD];
  __shared__ __attribute__((aligned(16))) unsigned short Bl[9*32*ICPAD];
  const int tid  = threadIdx.x;
  const int w    = tid >> 6;
  const int lane = tid & 63;
  const int lm   = lane & 15;
  const int q    = lane >> 4;
  const int y0   = blockIdx.x * 4;
  const int oc0  = blockIdx.y * 32;

  v4f acc[6][2];
  #pragma unroll
  for (int t = 0; t < 6; ++t)
    #pragma unroll
    for (int n = 0; n < 2; ++n)
      acc[t][n] = (v4f){0.f,0.f,0.f,0.f};

  u64 ra[19][2], rb[9][2];
  auto loadSlab = [&](int icg){
    #pragma unroll
    for (int n = 0; n < 19; ++n){
      int it = tid + 256*n;
      if (it < 4704){
        int i4 = it & 7, rc = it >> 3;
        int c = rc % 98, r = rc / 98;
        long src = ((long)((y0 + r)*PW + c) << 9) + icg*32 + i4*4;
        ra[n][0] = *reinterpret_cast<const u64*>(Xih + src);
        ra[n][1] = *reinterpret_cast<const u64*>(Xil + src);
      }
    }
    #pragma unroll
    for (int n = 0; n < 9; ++n){
      int it = tid + 256*n;
      if (it < 2304){
        int i4 = it & 7, to = it >> 3;
        int oc = to & 31, tap = to >> 5;
        long src = ((long)(tap*512 + oc0 + oc) << 9) + icg*32 + i4*4;
        rb[n][0] = *reinterpret_cast<const u64*>(Wh2 + src);
        rb[n][1] = *reinterpret_cast<const u64*>(Wl2 + src);
      }
    }
  };
  auto storeSlab = [&](){
    #pragma unroll
    for (int n = 0; n < 19; ++n){
      int it = tid + 256*n;
      if (it < 4704){
        int i4 = it & 7, rc = it >> 3;
        int dst = rc*ICPAD + i4*4;
        *reinterpret_cast<u64*>(Ah + dst) = ra[n][0];
        *reinterpret_cast<u64*>(Al + dst) = ra[n][1];
      }
    }
    #pragma unroll
    for (int n = 0; n < 9; ++n){
      int it = tid + 256*n;
      if (it < 2304){
        int i4 = it & 7, to = it >> 3;
        int dst = to*ICPAD + i4*4;
        *reinterpret_cast<u64*>(Bh + dst) = rb[n][0];
        *reinterpret_cast<u64*>(Bl + dst) = rb[n][1];
      }
    }
  };

  loadSlab(0);
  for (int icg = 0; icg < 16; ++icg){
    __syncthreads();
    storeSlab();
    __syncthreads();
    if (icg < 15) loadSlab(icg + 1);
    #pragma unroll
    for (int tap = 0; tap < 9; ++tap){
      const int dy = tap / 3, dx = tap - dy*3;
      v8s ah[6], al[6], bh[2], bl[2];
      #pragma unroll
      for (int t = 0; t < 6; ++t){
        int a = ((w + dy)*98 + 16*t + lm + dx)*ICPAD + q*8;
        ah[t] = *reinterpret_cast<const v8s*>(Ah + a);
        al[t] = *reinterpret_cast<const v8s*>(Al + a);
      }
      #pragma unroll
      for (int n = 0; n < 2; ++n){
        int a = (tap*32 + n*16 + lm)*ICPAD + q*8;
        bh[n] = *reinterpret_cast<const v8s*>(Bh + a);
        bl[n] = *reinterpret_cast<const v8s*>(Bl + a);
      }
      #pragma unroll
      for (int t = 0; t < 6; ++t)
        #pragma unroll
        for (int n = 0; n < 2; ++n){
          acc[t][n] = __builtin_amdgcn_mfma_f32_16x16x32_bf16(al[t], bl[n], acc[t][n], 0, 0, 0);
          acc[t][n] = __builtin_amdgcn_mfma_f32_16x16x32_bf16(al[t], bh[n], acc[t][n], 0, 0, 0);
          acc[t][n] = __builtin_amdgcn_mfma_f32_16x16x32_bf16(ah[t], bl[n], acc[t][n], 0, 0, 0);
          acc[t][n] = __builtin_amdgcn_mfma_f32_16x16x32_bf16(ah[t], bh[n], acc[t][n], 0, 0, 0);
        }
    }
  }
  const int yrow = y0 + w;
  #pragma unroll
  for (int n = 0; n < 2; ++n){
    int oc = oc0 + n*16 + lm;
    float b = Bc[oc];
    #pragma unroll
    for (int t = 0; t < 6; ++t){
      float4 v;
      v.x = fmaxf(acc[t][n].x + b, 0.f);
      v.y = fmaxf(acc[t][n].y + b, 0.f);
      v.z = fmaxf(acc[t][n].z + b, 0.f);
      v.w = fmaxf(acc[t][n].w + b, 0.f);
      *reinterpret_cast<float4*>(Y + (long)oc*HW + yrow*WW + 16*t + q*4) = v;
    }
  }
}

// ---------------- K2: 1x1 heads + softmax + box decode ----------------
// R34: register double-buffer of per-chunk Y/W loads (conv3-proven pattern): preload chunk
// c0+64 into regs during chunk c0's FMA loop. Pure load reordering -> bit-exact.
__global__ __launch_bounds__(256) void k_head(
    const float* __restrict__ Y, const float* __restrict__ Whd,
    const float* __restrict__ cb, const float* __restrict__ bb,
    const float* __restrict__ info,
    float* __restrict__ scores, float4* __restrict__ boxes, u32* __restrict__ hist8g)
{
  __shared__ float Ys[1024];
  __shared__ float Wsh[4096];   // transposed: Wsh[c*64 + (o&15)*4 + (o>>4)] = W[c][o]
  __shared__ u32 lh[256];
  const int tid = threadIdx.x;
  const int p0  = blockIdx.x * 16;
  const int po  = tid & 15;
  const int oj  = tid >> 4;
  lh[tid] = 0u;
  float accM[4], accC[4];
  #pragma unroll
  for (int k = 0; k < 4; ++k){ accM[k] = 0.f; accC[k] = 0.f; }

  float yreg[4], wreg[16];
  auto preload = [&](int c0){
    #pragma unroll
    for (int u = 0; u < 4; ++u){
      int i = tid + 256*u;
      yreg[u] = Y[(c0 + (i >> 4))*HW + p0 + (i & 15)];
    }
    #pragma unroll
    for (int u = 0; u < 16; ++u){
      int i = tid + 256*u;
      wreg[u] = Whd[(c0 + (i >> 6))*64 + (i & 63)];
    }
  };
  auto stash = [&](){
    #pragma unroll
    for (int u = 0; u < 4; ++u){
      int i = tid + 256*u;
      Ys[i] = yreg[u];
    }
    #pragma unroll
    for (int u = 0; u < 16; ++u){
      int i = tid + 256*u;
      int c = i >> 6, o = i & 63;
      Wsh[c*64 + (o & 15)*4 + (o >> 4)] = wreg[u];
    }
  };

  preload(0);
  for (int c0 = 0; c0 < CC; c0 += 64){
    __syncthreads();
    stash();
    __syncthreads();
    if (c0 + 64 < CC) preload(c0 + 64);
    #pragma unroll 4
    for (int c = 0; c < 64; ++c){
      float xa = Ys[c*16 + po];
      float4 wv = *reinterpret_cast<const float4*>(Wsh + c*64 + oj*4);
      accC[0] = __fmaf_rn(xa, wv.x, accC[0]);
      accC[1] = __fmaf_rn(xa, wv.y, accC[1]);
      accC[2] = __fmaf_rn(xa, wv.z, accC[2]);
      accC[3] = __fmaf_rn(xa, wv.w, accC[3]);
    }
    #pragma unroll
    for (int k = 0; k < 4; ++k){ accM[k] += accC[k]; accC[k] = 0.f; }
  }
  __syncthreads();
  #pragma unroll
  for (int k = 0; k < 4; ++k){
    int o = oj + 16*k;
    float bias = (o < 18) ? cb[o] : ((o < 54) ? bb[o - 18] : 0.f);
    Ys[po*64 + o] = accM[k] + bias;
  }
  __syncthreads();
  float imH = info[0], imW = info[1], imS = info[2];
  for (int it = tid; it < 144; it += 256){
    int pl = it / 9;
    int a  = it - pl*9;
    const float* L = Ys + pl*64;
    float l0 = L[a], l1 = L[9 + a];
    float mx = fmaxf(l0, l1);
    float e0 = expf(l0 - mx), e1 = expf(l1 - mx);
    float sc = e1 / (e0 + e1);
    float d0 = L[18 + a*4 + 0], d1 = L[18 + a*4 + 1];
    float d2 = L[18 + a*4 + 2], d3 = L[18 + a*4 + 3];
    int pos = p0 + pl;
    int yy = pos / 96;
    int xx = pos - yy * 96;
    float aw = c_aw[a], ah = c_ah[a];
    float acx = (float)(xx * 16 + 8);
    float acy = (float)(yy * 16 + 8);
    float cx = __fadd_rn(__fmul_rn(d0, aw), acx);
    float cy = __fadd_rn(__fmul_rn(d1, ah), acy);
    float pw = __fmul_rn(expf(d2), aw);
    float ph = __fmul_rn(expf(d3), ah);
    float hx = __fmul_rn(0.5f, pw);
    float hy = __fmul_rn(0.5f, ph);
    float x1 = fminf(fmaxf(__fadd_rn(cx, -hx), 0.f), imW - 1.f);
    float y1 = fminf(fmaxf(__fadd_rn(cy, -hy), 0.f), imH - 1.f);
    float x2 = fminf(fmaxf(__fadd_rn(cx,  hx), 0.f), imW - 1.f);
    float y2 = fminf(fmaxf(__fadd_rn(cy,  hy), 0.f), imH - 1.f);
    float ms = 16.f * imS;
    bool keep = ((x2 - x1 + 1.f) >= ms) && ((y2 - y1 + 1.f) >= ms);
    int g = pos * 9 + a;
    float val = keep ? sc : -__builtin_inff();
    scores[g] = val;
    boxes[g]  = make_float4(x1, y1, x2, y2);
    atomicAdd(&lh[sortkey(val) >> 24], 1u);   // LDS atomic, block-private
  }
  __syncthreads();
  hist8g[blockIdx.x*256 + tid] = lh[tid];     // plain coalesced store
}

// ---------- K3: fused selection — R34: hierarchical suffix scan (3 barriers vs 20) ----------
// The 1024-wide Hillis-Steele scan cost 20 full-block barriers on a 16-wave single-CU block.
// Replaced with intra-wave shfl suffix + wave-sum suffix; identical integer totals in cs[]
// -> identical selg/K32s -> bit-exact.
__global__ __launch_bounds__(1024) void k_sel(const u32* __restrict__ hist8g, u32* __restrict__ hist2,
                                              const float* __restrict__ scores,
                                              u32* __restrict__ ctr, u64* __restrict__ keys){
  __shared__ u32 cs[1024];
  __shared__ u32 bs[64];
  __shared__ u32 h8[256];
  __shared__ u32 lh2[256];
  __shared__ u32 wsum[16], wsfx[16];
  __shared__ int selg;
  __shared__ u32 afterv, T16s, aboves, K32s, B8s, above8s;
  const int t = threadIdx.x;
  const int lane = t & 63;
  const int wv   = t >> 6;
  const int b0 = t * 64;

  // ---- L1: merge per-block 256-bin partials ----
  { int g = t >> 8, bin = t & 255;
    u32 s = 0;
    for (int b = g; b < NHB; b += 4) s += hist8g[b*256 + bin];
    cs[t] = s; }
  __syncthreads();
  if (t < 256){
    h8[t] = cs[t] + cs[256 + t] + cs[512 + t] + cs[768 + t];
    lh2[t] = 0u;
  }
  __syncthreads();
  if (t == 0){
    u32 acc = 0;
    for (int bin = 255; bin >= 0; --bin){
      acc += h8[bin];
      if (acc >= 6000u){ B8s = (u32)bin; above8s = acc - h8[bin]; break; }
    }
  }
  __syncthreads();

  // ---- L2: 256-bin scan over next 8 bits among keys with top8 == B8 ----
  { u32 b8 = B8s;
    const float4* s4 = reinterpret_cast<const float4*>(scores);
    for (int i = t; i < NANCH/4; i += 1024){
      float4 v = s4[i];
      u32 k0 = sortkey(v.x), k1 = sortkey(v.y), k2 = sortkey(v.z), k3 = sortkey(v.w);
      if ((k0 >> 24) == b8) atomicAdd(&lh2[(k0 >> 16) & 0xFFu], 1u);
      if ((k1 >> 24) == b8) atomicAdd(&lh2[(k1 >> 16) & 0xFFu], 1u);
      if ((k2 >> 24) == b8) atomicAdd(&lh2[(k2 >> 16) & 0xFFu], 1u);
      if ((k3 >> 24) == b8) atomicAdd(&lh2[(k3 >> 16) & 0xFFu], 1u);
    } }
  __syncthreads();
  if (t == 0){
    u32 acc = above8s;
    for (int bin = 255; bin >= 0; --bin){
      acc += lh2[bin];
      if (acc >= 6000u){ T16s = (B8s << 8) | (u32)bin; aboves = acc - lh2[bin]; break; }
    }
  }
  __syncthreads();

  // ---- L3: hist2 over low 16 bits among keys with top16 == T16s ----
  { u32 pfx = T16s;
    const float4* s4 = reinterpret_cast<const float4*>(scores);
    for (int i = t; i < NANCH/4; i += 1024){
      float4 v = s4[i];
      u32 k0 = sortkey(v.x), k1 = sortkey(v.y), k2 = sortkey(v.z), k3 = sortkey(v.w);
      if ((k0 >> 16) == pfx) atomicAdd(&hist2[k0 & 0xFFFFu], 1u);
      if ((k1 >> 16) == pfx) atomicAdd(&hist2[k1 & 0xFFFFu], 1u);
      if ((k2 >> 16) == pfx) atomicAdd(&hist2[k2 & 0xFFFFu], 1u);
      if ((k3 >> 16) == pfx) atomicAdd(&hist2[k3 & 0xFFFFu], 1u);
    } }
  __threadfence();
  __syncthreads();

  if (t == 0) selg = -1;
  __syncthreads();
  const u32 target = 6000u - aboves;
  // hierarchical suffix scan: cs[t] = sum over j>=t of per-thread 64-bin sums
  { u32 s = 0;
    for (int i = 0; i < 64; ++i) s += hist2[b0 + i];
    u32 v = s;
    #pragma unroll
    for (int off = 1; off < 64; off <<= 1){
      u32 o = (u32)__shfl((int)v, lane + off, 64);
      if (lane + off < 64) v += o;
    }
    if (lane == 0) wsum[wv] = v;        // whole-wave sum
    __syncthreads();
    if (t < 16){
      u32 x = wsum[t];
      u32 vv = x;
      #pragma unroll
      for (int off = 1; off < 16; off <<= 1){
        u32 o = (u32)__shfl((int)vv, t + off, 64);
        if (t + off < 16) vv += o;
      }
      wsfx[t] = vv - x;                 // exclusive suffix over later waves
    }
    __syncthreads();
    cs[t] = v + wsfx[wv];
    __syncthreads();
  }
  { u32 here  = cs[t];
    u32 after = (t < 1023) ? cs[t + 1] : 0u;
    if (here >= target && after < target){ selg = t; afterv = after; } }
  __syncthreads();
  { int g = selg;
    if (g >= 0 && t < 64) bs[t] = hist2[g*64 + t];
    __syncthreads();
    if (t == 0){
      if (g < 0) K32s = (T16s << 16);
      else {
        u32 acc = afterv;
        for (int b = 63; b >= 0; --b){
          u32 h = bs[b];
          acc += h;
          if (acc >= target){ K32s = (T16s << 16) | (u32)(g*64 + b); break; }
        }
      }
      ctr[4] = 6000u;
    } }
  __syncthreads();

  // ---- compact: ballot-aggregated counter ----
  { u32 K = K32s;
    const float4* s4 = reinterpret_cast<const float4*>(scores);
    for (int i = t; i < NANCH/4; i += 1024){
      float4 v = s4[i];
      u32 kk[4] = {sortkey(v.x), sortkey(v.y), sortkey(v.z), sortkey(v.w)};
      u64 m[4];
      #pragma unroll
      for (int u = 0; u < 4; ++u) m[u] = __ballot(kk[u] >= K);
      u32 tot = (u32)(__popcll(m[0]) + __popcll(m[1]) + __popcll(m[2]) + __popcll(m[3]));
      if (tot){
        u32 base = 0;
        if (lane == 0) base = atomicAdd(&ctr[0], tot);
        base = (u32)__shfl((int)base, 0, 64);
        u64 below = ((u64)1 << lane) - 1;
        u32 off = 0;
        #pragma unroll
        for (int u = 0; u < 4; ++u){
          if (kk[u] >= K){
            u32 pos = base + off + (u32)__popcll(m[u] & below);
            if (pos < CAP) keys[pos] = ((u64)kk[u] << 32) | (u64)(u32)(~(u32)(i*4 + u));
          }
          off += (u32)__popcll(m[u]);
        }
      }
    } }
}

// ---------------- K-rank — R34: 256 blocks x 512 thr (all CUs; half per-thread LDS stream).
// 32 candidates/block, 16 half-segment scan; same rank definition (strict > over zero-padded
// CAP array) -> bit-exact. ----------------
__global__ __launch_bounds__(512) void k_rank(const u64* __restrict__ keys, u32* __restrict__ ctr,
                                              const float4* __restrict__ boxes,
                                              float4* __restrict__ topB, float* __restrict__ topA){
  __shared__ u64 ks[CAP];        // 64 KB
  __shared__ u32 part[16][32];
  const int t  = threadIdx.x;
  const int s  = t >> 5;         // half-segment 0..15
  const int k  = t & 31;
  const int gi = blockIdx.x * 32 + k;
  u32 count = ctr[0]; if (count > CAP) count = CAP;
  u64 my = (gi < (int)count) ? keys[gi] : 0ull;
  for (int j = t; j < CAP; j += 512)
    ks[j] = (j < (int)count) ? keys[j] : 0ull;
  __syncthreads();
  int rank = 0;
  { const ulonglong2* kp = reinterpret_cast<const ulonglong2*>(ks + s*512);
    #pragma unroll 8
    for (int j = 0; j < 256; ++j){
      ulonglong2 kv = kp[j];
      rank += (kv.x > my) + (kv.y > my);
    } }
  part[s][k] = (u32)rank;
  __syncthreads();
  int r = 0;
  if (t < 32){
    #pragma unroll
    for (int ss = 0; ss < 16; ++ss) r += part[ss][k];
  }
  bool sel = (t < 32) && (gi < (int)count) && (r < PRE);
  int myv = 0x7FFFFFFF;
  if (sel && !((my >> 32) & 0x80000000ull)) myv = r;
  if (t < 64){
    #pragma unroll
    for (int off = 32; off; off >>= 1){
      int o = __shfl_down(myv, off, 64);
      myv = (o < myv) ? o : myv;
    }
    if (t == 0 && myv != 0x7FFFFFFF) atomicMin((int*)(ctr + 4), myv);
  }
  if (sel){
    u32 idx = ~(u32)my;
    float4 bv = make_float4(0.f,0.f,0.f,0.f);
    float area = 1.f;
    if (idx < NANCH){
      bv = boxes[idx];
      area = (bv.z - bv.x + 1.f) * (bv.w - bv.y + 1.f);
    }
    topB[r] = bv;
    topA[r] = area;
  }
}

// ---------- K5: chunked exact NMS — R30-proven (91.4µs) ----------
__global__ __launch_bounds__(256) void k_nms3(const float4* __restrict__ topB,
                                              const u32* __restrict__ ctr, float* __restrict__ out){
  __shared__ float4 kb[POST];
  __shared__ float4 bx2[64];
  __shared__ u64    am[4];
  __shared__ int    nkS;
  const int tid  = threadIdx.x;
  const int wv   = tid >> 6;
  const int lane = tid & 63;
  int validN = (int)ctr[0];
  int finN   = (int)ctr[4];
  if (finN < validN) validN = finN;
  if (validN > PRE)  validN = PRE;
  if (tid == 0) nkS = 0;
  __syncthreads();

  float4 bnx = make_float4(0.f,0.f,0.f,0.f);
  if (lane < validN) bnx = topB[lane];

  for (int base = 0; base < validN; base += 64){
    int nk = nkS;
    if (nk >= POST) break;
    int c = base + lane;
    bool alive = (c < validN);
    float4 b = bnx;
    float ar = alive ? (b.z - b.x + 1.f) * (b.w - b.y + 1.f) : 1.f;
    if (wv == 0) bx2[lane] = b;
    { int cn = base + 64 + lane;
      if (cn < validN) bnx = topB[cn]; }
    int j = wv;
    for (; j + 28 < nk; j += 32){
      float4 kx[8];
      #pragma unroll
      for (int u = 0; u < 8; ++u) kx[u] = kb[j + 4*u];
      #pragma unroll
      for (int u = 0; u < 8; ++u){
        float kar = (kx[u].z - kx[u].x + 1.f) * (kx[u].w - kx[u].y + 1.f);
        float xx1 = fmaxf(kx[u].x, b.x);
        float yy1 = fmaxf(kx[u].y, b.y);
        float xx2 = fminf(kx[u].z, b.z);
        float yy2 = fminf(kx[u].w, b.w);
        float iw = fmaxf(xx2 - xx1 + 1.f, 0.f);
        float ih = fmaxf(yy2 - yy1 + 1.f, 0.f);
        float inter = iw * ih;
        float iou = inter / (kar + ar - inter);
        if (iou > 0.7f) alive = false;
      }
    }
    for (; j < nk; j += 4){
      float4 kbx = kb[j];
      float kar = (kbx.z - kbx.x + 1.f) * (kbx.w - kbx.y + 1.f);
      float xx1 = fmaxf(kbx.x, b.x);
      float yy1 = fmaxf(kbx.y, b.y);
      float xx2 = fminf(kbx.z, b.z);
      float yy2 = fminf(kbx.w, b.w);
      float iw = fmaxf(xx2 - xx1 + 1.f, 0.f);
      float ih = fmaxf(yy2 - yy1 + 1.f, 0.f);
      float inter = iw * ih;
      float iou = inter / (kar + ar - inter);
      if (iou > 0.7f) alive = false;
    }
    { u64 bal = __ballot(alive);
      if (lane == 0) am[wv] = bal; }
    __syncthreads();
    if (wv == 0){
      u64 comb = am[0] & am[1] & am[2] & am[3];
      alive = ((comb >> lane) & 1ull) != 0ull;
      int nkl = nk;
      while (nkl < POST){
        u64 bal = __ballot(alive);
        if (!bal) break;
        int L = (int)__ffsll((unsigned long long)bal) - 1;
        float4 pb = bx2[L];
        float pa = (pb.z - pb.x + 1.f) * (pb.w - pb.y + 1.f);
        if (lane == 0) kb[nkl] = pb;
        nkl++;
        if (lane == L) alive = false;
        if (alive){
          float xx1 = fmaxf(pb.x, b.x);
          float yy1 = fmaxf(pb.y, b.y);
          float xx2 = fminf(pb.z, b.z);
          float yy2 = fminf(pb.w, b.w);
          float iw = fmaxf(xx2 - xx1 + 1.f, 0.f);
          float ih = fmaxf(yy2 - yy1 + 1.f, 0.f);
          float inter = iw * ih;
          float iou = inter / (pa + ar - inter);
          if (iou > 0.7f) alive = false;
        }
      }
      if (lane == 0) nkS = nkl;
    }
    __syncthreads();
  }
  int nk = nkS;
  for (int q = tid; q < 1500; q += 256){
    int r = q / 5, c = q - r*5;
    float v = 0.f;
    if (r < nk && c > 0){
      float4 bx = kb[r];
      v = (c == 1) ? bx.x : (c == 2) ? bx.y : (c == 3) ? bx.z : bx.w;
    }
    out[q] = v;
  }
}

// ---------------- launch ----------------
extern "C" void kernel_launch(void* const* d_in, const int* in_sizes, int n_in,
                              void* d_out, int out_size, void* d_ws, size_t ws_size,
                              hipStream_t stream)
{
  const float* fm   = (const float*)d_in[0];
  const float* info = (const float*)d_in[1];
  const float* cw3  = (const float*)d_in[2];
  const float* cb3  = (const float*)d_in[3];
  const float* clw  = (const float*)d_in[4];
  const float* clb  = (const float*)d_in[5];
  const float* bbw  = (const float*)d_in[6];
  const float* bbb  = (const float*)d_in[7];
  float* out = (float*)d_out;

  char* base = (char*)d_ws;
  u32*   hist8g = (u32*)  (base + 0);          // 384*256 u32 = 393216 B
  u32*   hist2  = (u32*)  (base + 393216);     // 65536 u32  = 262144 B
  u32*   ctr    = (u32*)  (base + 655360);     // 16 u32: [0]=count [4]=finiteN
  float* Y      = (float*)(base + 655424);     // 12582912 B -> ends 13238336
  float* scores = (float*)(base + 13238336);   // 221184 B  -> ends 13459520
  float4* boxes = (float4*)(base + 13459520);  // 884736 B  -> ends 14344256
  u64*   keys   = (u64*)  (base + 14344256);   // 65536 B   -> ends 14409792
  float4* topB  = (float4*)(base + 14409792);  // 6000*16 = 96000 B -> ends 14505792
  float* topA   = (float*)(base + 14505792);   // 6000*4  = 24000 B -> ends 14529792
  unsigned short* Xih = (unsigned short*)(base + 14529792);  // 6623232 B -> ends 21153024
  unsigned short* Xil = (unsigned short*)(base + 21153024);  // 6623232 B -> ends 27776256
  unsigned short* Wh2 = (unsigned short*)(base + 27776256);  // 4718592 B -> ends 32494848
  unsigned short* Wl2 = (unsigned short*)(base + 32494848);  // 4718592 B -> ends 37213440
  float* Whd = (float*)(base + 37213440);      // 512*64 f32 -> ends 37344512
  // total ws use: ~37.3 MB

  k_cvt   <<<1168, 256, 0, stream>>>(fm, cw3, clw, bbw, Xih, Xil, Wh2, Wl2, Whd, (u32*)base);
  k_conv3 <<<dim3(16, 16), 256, 0, stream>>>(Xih, Xil, Wh2, Wl2, cb3, Y);
  k_head  <<<384, 256, 0, stream>>>(Y, Whd, clb, bbb, info, scores, boxes, hist8g);
  k_sel   <<<1,  1024, 0, stream>>>(hist8g, hist2, scores, ctr, keys);
  k_rank  <<<256, 512, 0, stream>>>(keys, ctr, boxes, topB, topA);
  k_nms3  <<<1,   256, 0, stream>>>(topB, ctr, out);
}

// Round 13
// 359.164 us; speedup vs baseline: 1.5549x; 1.0001x over previous
//
#include <hip/hip_runtime.h>
#include <stdint.h>

typedef unsigned int u32;
typedef unsigned long long u64;
typedef __attribute__((ext_vector_type(8))) short v8s;   // 8 bf16 = 4 VGPR (MFMA A/B frag)
typedef __attribute__((ext_vector_type(4))) float v4f;   // MFMA C/D frag

#define HH 64
#define WW 96
#define HW 6144
#define CC 512
#define NANCH 55296
#define PRE 6000
#define POST 300
#define CAP 8192
#define PW 98
#define PH 66
#define NHB 384          // k_head blocks (hist8g partials)
#define AQ 590           // A q-region stride (588 rows + 2 pad), 8-short units
#define BQ 290           // B q-region stride (288 rows + 2 pad)

__device__ __constant__ float c_aw[9] = {184.f,368.f,736.f,128.f,256.f,512.f,88.f,176.f,352.f};
__device__ __constant__ float c_ah[9] = {96.f,192.f,384.f,128.f,256.f,512.f,176.f,352.f,704.f};

__device__ __forceinline__ unsigned short bf16_rne(float x){
  u32 u = __float_as_uint(x);
  return (unsigned short)((u + 0x7FFFu + ((u >> 16) & 1u)) >> 16);
}
__device__ __forceinline__ u32 sortkey(float s){
  u32 u = __float_as_uint(s);
  return u ^ ((u & 0x80000000u) ? 0xFFFFFFFFu : 0x80000000u);
}

// ---------- K0: merged convert + zeroing — R29: u64-packed bf16 hi/lo stores ----------
__global__ __launch_bounds__(256) void k_cvt(const float* __restrict__ X, const float* __restrict__ Wt,
                                             const float* __restrict__ cw, const float* __restrict__ bw,
                                             unsigned short* __restrict__ Xih, unsigned short* __restrict__ Xil,
                                             unsigned short* __restrict__ Wh2, unsigned short* __restrict__ Wl2,
                                             float* __restrict__ Whd, u32* __restrict__ zero_region){
  __shared__ float Ls[64][97];
  __shared__ float Ws[4608];
  const int b = blockIdx.x, tid = threadIdx.x;
  { int gid = b*256 + tid;
    if (gid < 163856) zero_region[gid] = 0u; }   // hist8g (98304) + hist2 (65536) + ctr (16)
  if (b < 528){
    const int rp  = b % 66;
    const int ic0 = (b / 66) * 64;
    const bool zrow = (rp == 0 || rp == PH-1);
    if (!zrow){
      int r = rp - 1;
      for (int i = tid; i < 6144; i += 256){
        int ii = i / 96, c = i - ii*96;
        Ls[ii][c] = X[(ic0+ii)*HW + r*WW + c];
      }
    }
    __syncthreads();
    for (int idx = tid; idx < 98*16; idx += 256){
      int cp = idx >> 4, g = idx & 15;
      int icl0 = g*4;
      u64 hv = 0, lv = 0;
      #pragma unroll
      for (int u = 0; u < 4; ++u){
        float x = 0.f;
        if (!zrow && cp >= 1 && cp <= 96) x = Ls[icl0+u][cp-1];
        unsigned short h = bf16_rne(x);
        float hf = __uint_as_float(((u32)h) << 16);
        unsigned short l = bf16_rne(x - hf);
        hv |= ((u64)h) << (16*u);
        lv |= ((u64)l) << (16*u);
      }
      long o = ((long)(rp*PW + cp) << 9) + ic0 + icl0;
      *reinterpret_cast<u64*>(Xih + o) = hv;
      *reinterpret_cast<u64*>(Xil + o) = lv;
    }
  } else if (b < 1040){
    const int oc = b - 528;
    for (int i = tid; i < 4608; i += 256) Ws[i] = Wt[oc*4608 + i];
    __syncthreads();
    for (int idx = tid; idx < 9*128; idx += 256){
      int tap = idx >> 7, g = idx & 127;
      int icb = g*4;
      u64 hv = 0, lv = 0;
      #pragma unroll
      for (int u = 0; u < 4; ++u){
        float x = Ws[(icb+u)*9 + tap];
        unsigned short h = bf16_rne(x);
        float hf = __uint_as_float(((u32)h) << 16);
        unsigned short l = bf16_rne(x - hf);
        hv |= ((u64)h) << (16*u);
        lv |= ((u64)l) << (16*u);
      }
      long o = ((long)(tap*512 + oc) << 9) + icb;
      *reinterpret_cast<u64*>(Wh2 + o) = hv;
      *reinterpret_cast<u64*>(Wl2 + o) = lv;
    }
  } else {
    // head-weight transpose: Whd[gc*64 + o]
    int idx = (b - 1040)*256 + tid;
    int o  = idx >> 9;
    int gc = idx & 511;
    float v = 0.f;
    if (o < 18) v = cw[o*512 + gc];
    else if (o < 54) v = bw[(o-18)*512 + gc];
    Whd[gc*64 + o] = v;
  }
}

// ---------- K1: MFMA conv — R35: K-major LDS layout (conflict fix) ----------
// Counter evidence: SQ_LDS_BANK_CONFLICT = 1.303e7/dispatch = ~50k extra cyc/CU (~21µs of
// the 120µs). Row-major 80B-stride rows put 16-lane fragment reads on 8 bank windows with
// distinct addresses. New layout: per q (K-window), contiguous 16B units indexed by row:
// addr = (q*REGION + row)*16B. 16-lane reads become 256B contiguous (free 2-way); region
// strides 590/290 de-align q-groups. Fragment CONTENTS unchanged -> bit-identical Y.
__global__ __launch_bounds__(256, 1) void k_conv3(
    const unsigned short* __restrict__ Xih, const unsigned short* __restrict__ Xil,
    const unsigned short* __restrict__ Wh2, const unsigned short* __restrict__ Wl2,
    const float* __restrict__ Bc, float* __restrict__ Y)
{
  __shared__ __attribute__((aligned(16))) unsigned short Ah[4*AQ*8];   // 37760 B
  __shared__ __attribute__((aligned(16))) unsigned short Al[4*AQ*8];
  __shared__ __attribute__((aligned(16))) unsigned short Bh[4*BQ*8];   // 18560 B
  __shared__ __attribute__((aligned(16))) unsigned short Bl[4*BQ*8];
  const int tid  = threadIdx.x;
  const int w    = tid >> 6;
  const int lane = tid & 63;
  const int lm   = lane & 15;
  const int q    = lane >> 4;
  const int y0   = blockIdx.x * 4;
  const int oc0  = blockIdx.y * 32;

  v4f acc[6][2];
  #pragma unroll
  for (int t = 0; t < 6; ++t)
    #pragma unroll
    for (int n = 0; n < 2; ++n)
      acc[t][n] = (v4f){0.f,0.f,0.f,0.f};

  u64 ra[19][2], rb[9][2];
  auto loadSlab = [&](int icg){
    #pragma unroll
    for (int n = 0; n < 19; ++n){
      int it = tid + 256*n;
      if (it < 4704){
        int i4 = it & 7, rc = it >> 3;
        int c = rc % 98, r = rc / 98;
        long src = ((long)((y0 + r)*PW + c) << 9) + icg*32 + i4*4;
        ra[n][0] = *reinterpret_cast<const u64*>(Xih + src);
        ra[n][1] = *reinterpret_cast<const u64*>(Xil + src);
      }
    }
    #pragma unroll
    for (int n = 0; n < 9; ++n){
      int it = tid + 256*n;
      if (it < 2304){
        int i4 = it & 7, to = it >> 3;
        int oc = to & 31, tap = to >> 5;
        long src = ((long)(tap*512 + oc0 + oc) << 9) + icg*32 + i4*4;
        rb[n][0] = *reinterpret_cast<const u64*>(Wh2 + src);
        rb[n][1] = *reinterpret_cast<const u64*>(Wl2 + src);
      }
    }
  };
  auto storeSlab = [&](){
    #pragma unroll
    for (int n = 0; n < 19; ++n){
      int it = tid + 256*n;
      if (it < 4704){
        int i4 = it & 7, rc = it >> 3;
        // shorts for ic = i4*4..i4*4+3 -> q-region i4>>1, within-unit half i4&1
        int dst = ((i4 >> 1)*AQ + rc)*8 + (i4 & 1)*4;
        *reinterpret_cast<u64*>(Ah + dst) = ra[n][0];
        *reinterpret_cast<u64*>(Al + dst) = ra[n][1];
      }
    }
    #pragma unroll
    for (int n = 0; n < 9; ++n){
      int it = tid + 256*n;
      if (it < 2304){
        int i4 = it & 7, to = it >> 3;
        int dst = ((i4 >> 1)*BQ + to)*8 + (i4 & 1)*4;
        *reinterpret_cast<u64*>(Bh + dst) = rb[n][0];
        *reinterpret_cast<u64*>(Bl + dst) = rb[n][1];
      }
    }
  };

  loadSlab(0);
  for (int icg = 0; icg < 16; ++icg){
    __syncthreads();
    storeSlab();
    __syncthreads();
    if (icg < 15) loadSlab(icg + 1);
    #pragma unroll
    for (int tap = 0; tap < 9; ++tap){
      const int dy = tap / 3, dx = tap - dy*3;
      v8s ah[6], al[6], bh[2], bl[2];
      #pragma unroll
      for (int t = 0; t < 6; ++t){
        int a = (q*AQ + (w + dy)*98 + 16*t + lm + dx)*8;
        ah[t] = *reinterpret_cast<const v8s*>(Ah + a);
        al[t] = *reinterpret_cast<const v8s*>(Al + a);
      }
      #pragma unroll
      for (int n = 0; n < 2; ++n){
        int a = (q*BQ + tap*32 + n*16 + lm)*8;
        bh[n] = *reinterpret_cast<const v8s*>(Bh + a);
        bl[n] = *reinterpret_cast<const v8s*>(Bl + a);
      }
      #pragma unroll
      for (int t = 0; t < 6; ++t)
        #pragma unroll
        for (int n = 0; n < 2; ++n){
          acc[t][n] = __builtin_amdgcn_mfma_f32_16x16x32_bf16(al[t], bl[n], acc[t][n], 0, 0, 0);
          acc[t][n] = __builtin_amdgcn_mfma_f32_16x16x32_bf16(al[t], bh[n], acc[t][n], 0, 0, 0);
          acc[t][n] = __builtin_amdgcn_mfma_f32_16x16x32_bf16(ah[t], bl[n], acc[t][n], 0, 0, 0);
          acc[t][n] = __builtin_amdgcn_mfma_f32_16x16x32_bf16(ah[t], bh[n], acc[t][n], 0, 0, 0);
        }
    }
  }
  const int yrow = y0 + w;
  #pragma unroll
  for (int n = 0; n < 2; ++n){
    int oc = oc0 + n*16 + lm;
    float b = Bc[oc];
    #pragma unroll
    for (int t = 0; t < 6; ++t){
      float4 v;
      v.x = fmaxf(acc[t][n].x + b, 0.f);
      v.y = fmaxf(acc[t][n].y + b, 0.f);
      v.z = fmaxf(acc[t][n].z + b, 0.f);
      v.w = fmaxf(acc[t][n].w + b, 0.f);
      *reinterpret_cast<float4*>(Y + (long)oc*HW + yrow*WW + 16*t + q*4) = v;
    }
  }
}

// ---------------- K2: 1x1 heads + softmax + box decode (R34: reg double-buffer) ----------------
__global__ __launch_bounds__(256) void k_head(
    const float* __restrict__ Y, const float* __restrict__ Whd,
    const float* __restrict__ cb, const float* __restrict__ bb,
    const float* __restrict__ info,
    float* __restrict__ scores, float4* __restrict__ boxes, u32* __restrict__ hist8g)
{
  __shared__ float Ys[1024];
  __shared__ float Wsh[4096];   // transposed: Wsh[c*64 + (o&15)*4 + (o>>4)] = W[c][o]
  __shared__ u32 lh[256];
  const int tid = threadIdx.x;
  const int p0  = blockIdx.x * 16;
  const int po  = tid & 15;
  const int oj  = tid >> 4;
  lh[tid] = 0u;
  float accM[4], accC[4];
  #pragma unroll
  for (int k = 0; k < 4; ++k){ accM[k] = 0.f; accC[k] = 0.f; }

  float yreg[4], wreg[16];
  auto preload = [&](int c0){
    #pragma unroll
    for (int u = 0; u < 4; ++u){
      int i = tid + 256*u;
      yreg[u] = Y[(c0 + (i >> 4))*HW + p0 + (i & 15)];
    }
    #pragma unroll
    for (int u = 0; u < 16; ++u){
      int i = tid + 256*u;
      wreg[u] = Whd[(c0 + (i >> 6))*64 + (i & 63)];
    }
  };
  auto stash = [&](){
    #pragma unroll
    for (int u = 0; u < 4; ++u){
      int i = tid + 256*u;
      Ys[i] = yreg[u];
    }
    #pragma unroll
    for (int u = 0; u < 16; ++u){
      int i = tid + 256*u;
      int c = i >> 6, o = i & 63;
      Wsh[c*64 + (o & 15)*4 + (o >> 4)] = wreg[u];
    }
  };

  preload(0);
  for (int c0 = 0; c0 < CC; c0 += 64){
    __syncthreads();
    stash();
    __syncthreads();
    if (c0 + 64 < CC) preload(c0 + 64);
    #pragma unroll 4
    for (int c = 0; c < 64; ++c){
      float xa = Ys[c*16 + po];
      float4 wv = *reinterpret_cast<const float4*>(Wsh + c*64 + oj*4);
      accC[0] = __fmaf_rn(xa, wv.x, accC[0]);
      accC[1] = __fmaf_rn(xa, wv.y, accC[1]);
      accC[2] = __fmaf_rn(xa, wv.z, accC[2]);
      accC[3] = __fmaf_rn(xa, wv.w, accC[3]);
    }
    #pragma unroll
    for (int k = 0; k < 4; ++k){ accM[k] += accC[k]; accC[k] = 0.f; }
  }
  __syncthreads();
  #pragma unroll
  for (int k = 0; k < 4; ++k){
    int o = oj + 16*k;
    float bias = (o < 18) ? cb[o] : ((o < 54) ? bb[o - 18] : 0.f);
    Ys[po*64 + o] = accM[k] + bias;
  }
  __syncthreads();
  float imH = info[0], imW = info[1], imS = info[2];
  for (int it = tid; it < 144; it += 256){
    int pl = it / 9;
    int a  = it - pl*9;
    const float* L = Ys + pl*64;
    float l0 = L[a], l1 = L[9 + a];
    float mx = fmaxf(l0, l1);
    float e0 = expf(l0 - mx), e1 = expf(l1 - mx);
    float sc = e1 / (e0 + e1);
    float d0 = L[18 + a*4 + 0], d1 = L[18 + a*4 + 1];
    float d2 = L[18 + a*4 + 2], d3 = L[18 + a*4 + 3];
    int pos = p0 + pl;
    int yy = pos / 96;
    int xx = pos - yy * 96;
    float aw = c_aw[a], ah = c_ah[a];
    float acx = (float)(xx * 16 + 8);
    float acy = (float)(yy * 16 + 8);
    float cx = __fadd_rn(__fmul_rn(d0, aw), acx);
    float cy = __fadd_rn(__fmul_rn(d1, ah), acy);
    float pw = __fmul_rn(expf(d2), aw);
    float ph = __fmul_rn(expf(d3), ah);
    float hx = __fmul_rn(0.5f, pw);
    float hy = __fmul_rn(0.5f, ph);
    float x1 = fminf(fmaxf(__fadd_rn(cx, -hx), 0.f), imW - 1.f);
    float y1 = fminf(fmaxf(__fadd_rn(cy, -hy), 0.f), imH - 1.f);
    float x2 = fminf(fmaxf(__fadd_rn(cx,  hx), 0.f), imW - 1.f);
    float y2 = fminf(fmaxf(__fadd_rn(cy,  hy), 0.f), imH - 1.f);
    float ms = 16.f * imS;
    bool keep = ((x2 - x1 + 1.f) >= ms) && ((y2 - y1 + 1.f) >= ms);
    int g = pos * 9 + a;
    float val = keep ? sc : -__builtin_inff();
    scores[g] = val;
    boxes[g]  = make_float4(x1, y1, x2, y2);
    atomicAdd(&lh[sortkey(val) >> 24], 1u);   // LDS atomic, block-private
  }
  __syncthreads();
  hist8g[blockIdx.x*256 + tid] = lh[tid];     // plain coalesced store
}

// ---------- K3: fused selection — R34: hierarchical suffix scan (3 barriers vs 20) ----------
__global__ __launch_bounds__(1024) void k_sel(const u32* __restrict__ hist8g, u32* __restrict__ hist2,
                                              const float* __restrict__ scores,
                                              u32* __restrict__ ctr, u64* __restrict__ keys){
  __shared__ u32 cs[1024];
  __shared__ u32 bs[64];
  __shared__ u32 h8[256];
  __shared__ u32 lh2[256];
  __shared__ u32 wsum[16], wsfx[16];
  __shared__ int selg;
  __shared__ u32 afterv, T16s, aboves, K32s, B8s, above8s;
  const int t = threadIdx.x;
  const int lane = t & 63;
  const int wv   = t >> 6;
  const int b0 = t * 64;

  // ---- L1: merge per-block 256-bin partials ----
  { int g = t >> 8, bin = t & 255;
    u32 s = 0;
    for (int b = g; b < NHB; b += 4) s += hist8g[b*256 + bin];
    cs[t] = s; }
  __syncthreads();
  if (t < 256){
    h8[t] = cs[t] + cs[256 + t] + cs[512 + t] + cs[768 + t];
    lh2[t] = 0u;
  }
  __syncthreads();
  if (t == 0){
    u32 acc = 0;
    for (int bin = 255; bin >= 0; --bin){
      acc += h8[bin];
      if (acc >= 6000u){ B8s = (u32)bin; above8s = acc - h8[bin]; break; }
    }
  }
  __syncthreads();

  // ---- L2: 256-bin scan over next 8 bits among keys with top8 == B8 ----
  { u32 b8 = B8s;
    const float4* s4 = reinterpret_cast<const float4*>(scores);
    for (int i = t; i < NANCH/4; i += 1024){
      float4 v = s4[i];
      u32 k0 = sortkey(v.x), k1 = sortkey(v.y), k2 = sortkey(v.z), k3 = sortkey(v.w);
      if ((k0 >> 24) == b8) atomicAdd(&lh2[(k0 >> 16) & 0xFFu], 1u);
      if ((k1 >> 24) == b8) atomicAdd(&lh2[(k1 >> 16) & 0xFFu], 1u);
      if ((k2 >> 24) == b8) atomicAdd(&lh2[(k2 >> 16) & 0xFFu], 1u);
      if ((k3 >> 24) == b8) atomicAdd(&lh2[(k3 >> 16) & 0xFFu], 1u);
    } }
  __syncthreads();
  if (t == 0){
    u32 acc = above8s;
    for (int bin = 255; bin >= 0; --bin){
      acc += lh2[bin];
      if (acc >= 6000u){ T16s = (B8s << 8) | (u32)bin; aboves = acc - lh2[bin]; break; }
    }
  }
  __syncthreads();

  // ---- L3: hist2 over low 16 bits among keys with top16 == T16s ----
  { u32 pfx = T16s;
    const float4* s4 = reinterpret_cast<const float4*>(scores);
    for (int i = t; i < NANCH/4; i += 1024){
      float4 v = s4[i];
      u32 k0 = sortkey(v.x), k1 = sortkey(v.y), k2 = sortkey(v.z), k3 = sortkey(v.w);
      if ((k0 >> 16) == pfx) atomicAdd(&hist2[k0 & 0xFFFFu], 1u);
      if ((k1 >> 16) == pfx) atomicAdd(&hist2[k1 & 0xFFFFu], 1u);
      if ((k2 >> 16) == pfx) atomicAdd(&hist2[k2 & 0xFFFFu], 1u);
      if ((k3 >> 16) == pfx) atomicAdd(&hist2[k3 & 0xFFFFu], 1u);
    } }
  __threadfence();
  __syncthreads();

  if (t == 0) selg = -1;
  __syncthreads();
  const u32 target = 6000u - aboves;
  // hierarchical suffix scan: cs[t] = sum over j>=t of per-thread 64-bin sums
  { u32 s = 0;
    for (int i = 0; i < 64; ++i) s += hist2[b0 + i];
    u32 v = s;
    #pragma unroll
    for (int off = 1; off < 64; off <<= 1){
      u32 o = (u32)__shfl((int)v, lane + off, 64);
      if (lane + off < 64) v += o;
    }
    if (lane == 0) wsum[wv] = v;        // whole-wave sum
    __syncthreads();
    if (t < 16){
      u32 x = wsum[t];
      u32 vv = x;
      #pragma unroll
      for (int off = 1; off < 16; off <<= 1){
        u32 o = (u32)__shfl((int)vv, t + off, 64);
        if (t + off < 16) vv += o;
      }
      wsfx[t] = vv - x;                 // exclusive suffix over later waves
    }
    __syncthreads();
    cs[t] = v + wsfx[wv];
    __syncthreads();
  }
  { u32 here  = cs[t];
    u32 after = (t < 1023) ? cs[t + 1] : 0u;
    if (here >= target && after < target){ selg = t; afterv = after; } }
  __syncthreads();
  { int g = selg;
    if (g >= 0 && t < 64) bs[t] = hist2[g*64 + t];
    __syncthreads();
    if (t == 0){
      if (g < 0) K32s = (T16s << 16);
      else {
        u32 acc = afterv;
        for (int b = 63; b >= 0; --b){
          u32 h = bs[b];
          acc += h;
          if (acc >= target){ K32s = (T16s << 16) | (u32)(g*64 + b); break; }
        }
      }
      ctr[4] = 6000u;
    } }
  __syncthreads();

  // ---- compact: ballot-aggregated counter ----
  { u32 K = K32s;
    const float4* s4 = reinterpret_cast<const float4*>(scores);
    for (int i = t; i < NANCH/4; i += 1024){
      float4 v = s4[i];
      u32 kk[4] = {sortkey(v.x), sortkey(v.y), sortkey(v.z), sortkey(v.w)};
      u64 m[4];
      #pragma unroll
      for (int u = 0; u < 4; ++u) m[u] = __ballot(kk[u] >= K);
      u32 tot = (u32)(__popcll(m[0]) + __popcll(m[1]) + __popcll(m[2]) + __popcll(m[3]));
      if (tot){
        u32 base = 0;
        if (lane == 0) base = atomicAdd(&ctr[0], tot);
        base = (u32)__shfl((int)base, 0, 64);
        u64 below = ((u64)1 << lane) - 1;
        u32 off = 0;
        #pragma unroll
        for (int u = 0; u < 4; ++u){
          if (kk[u] >= K){
            u32 pos = base + off + (u32)__popcll(m[u] & below);
            if (pos < CAP) keys[pos] = ((u64)kk[u] << 32) | (u64)(u32)(~(u32)(i*4 + u));
          }
          off += (u32)__popcll(m[u]);
        }
      }
    } }
}

// ---------------- K-rank — R34: 256 blocks x 512 thr (proven) ----------------
__global__ __launch_bounds__(512) void k_rank(const u64* __restrict__ keys, u32* __restrict__ ctr,
                                              const float4* __restrict__ boxes,
                                              float4* __restrict__ topB, float* __restrict__ topA){
  __shared__ u64 ks[CAP];        // 64 KB
  __shared__ u32 part[16][32];
  const int t  = threadIdx.x;
  const int s  = t >> 5;         // half-segment 0..15
  const int k  = t & 31;
  const int gi = blockIdx.x * 32 + k;
  u32 count = ctr[0]; if (count > CAP) count = CAP;
  u64 my = (gi < (int)count) ? keys[gi] : 0ull;
  for (int j = t; j < CAP; j += 512)
    ks[j] = (j < (int)count) ? keys[j] : 0ull;
  __syncthreads();
  int rank = 0;
  { const ulonglong2* kp = reinterpret_cast<const ulonglong2*>(ks + s*512);
    #pragma unroll 8
    for (int j = 0; j < 256; ++j){
      ulonglong2 kv = kp[j];
      rank += (kv.x > my) + (kv.y > my);
    } }
  part[s][k] = (u32)rank;
  __syncthreads();
  int r = 0;
  if (t < 32){
    #pragma unroll
    for (int ss = 0; ss < 16; ++ss) r += part[ss][k];
  }
  bool sel = (t < 32) && (gi < (int)count) && (r < PRE);
  int myv = 0x7FFFFFFF;
  if (sel && !((my >> 32) & 0x80000000ull)) myv = r;
  if (t < 64){
    #pragma unroll
    for (int off = 32; off; off >>= 1){
      int o = __shfl_down(myv, off, 64);
      myv = (o < myv) ? o : myv;
    }
    if (t == 0 && myv != 0x7FFFFFFF) atomicMin((int*)(ctr + 4), myv);
  }
  if (sel){
    u32 idx = ~(u32)my;
    float4 bv = make_float4(0.f,0.f,0.f,0.f);
    float area = 1.f;
    if (idx < NANCH){
      bv = boxes[idx];
      area = (bv.z - bv.x + 1.f) * (bv.w - bv.y + 1.f);
    }
    topB[r] = bv;
    topA[r] = area;
  }
}

// ---------- K5: chunked exact NMS — R30-proven (91.4µs) ----------
__global__ __launch_bounds__(256) void k_nms3(const float4* __restrict__ topB,
                                              const u32* __restrict__ ctr, float* __restrict__ out){
  __shared__ float4 kb[POST];
  __shared__ float4 bx2[64];
  __shared__ u64    am[4];
  __shared__ int    nkS;
  const int tid  = threadIdx.x;
  const int wv   = tid >> 6;
  const int lane = tid & 63;
  int validN = (int)ctr[0];
  int finN   = (int)ctr[4];
  if (finN < validN) validN = finN;
  if (validN > PRE)  validN = PRE;
  if (tid == 0) nkS = 0;
  __syncthreads();

  float4 bnx = make_float4(0.f,0.f,0.f,0.f);
  if (lane < validN) bnx = topB[lane];

  for (int base = 0; base < validN; base += 64){
    int nk = nkS;
    if (nk >= POST) break;
    int c = base + lane;
    bool alive = (c < validN);
    float4 b = bnx;
    float ar = alive ? (b.z - b.x + 1.f) * (b.w - b.y + 1.f) : 1.f;
    if (wv == 0) bx2[lane] = b;
    { int cn = base + 64 + lane;
      if (cn < validN) bnx = topB[cn]; }
    int j = wv;
    for (; j + 28 < nk; j += 32){
      float4 kx[8];
      #pragma unroll
      for (int u = 0; u < 8; ++u) kx[u] = kb[j + 4*u];
      #pragma unroll
      for (int u = 0; u < 8; ++u){
        float kar = (kx[u].z - kx[u].x + 1.f) * (kx[u].w - kx[u].y + 1.f);
        float xx1 = fmaxf(kx[u].x, b.x);
        float yy1 = fmaxf(kx[u].y, b.y);
        float xx2 = fminf(kx[u].z, b.z);
        float yy2 = fminf(kx[u].w, b.w);
        float iw = fmaxf(xx2 - xx1 + 1.f, 0.f);
        float ih = fmaxf(yy2 - yy1 + 1.f, 0.f);
        float inter = iw * ih;
        float iou = inter / (kar + ar - inter);
        if (iou > 0.7f) alive = false;
      }
    }
    for (; j < nk; j += 4){
      float4 kbx = kb[j];
      float kar = (kbx.z - kbx.x + 1.f) * (kbx.w - kbx.y + 1.f);
      float xx1 = fmaxf(kbx.x, b.x);
      float yy1 = fmaxf(kbx.y, b.y);
      float xx2 = fminf(kbx.z, b.z);
      float yy2 = fminf(kbx.w, b.w);
      float iw = fmaxf(xx2 - xx1 + 1.f, 0.f);
      float ih = fmaxf(yy2 - yy1 + 1.f, 0.f);
      float inter = iw * ih;
      float iou = inter / (kar + ar - inter);
      if (iou > 0.7f) alive = false;
    }
    { u64 bal = __ballot(alive);
      if (lane == 0) am[wv] = bal; }
    __syncthreads();
    if (wv == 0){
      u64 comb = am[0] & am[1] & am[2] & am[3];
      alive = ((comb >> lane) & 1ull) != 0ull;
      int nkl = nk;
      while (nkl < POST){
        u64 bal = __ballot(alive);
        if (!bal) break;
        int L = (int)__ffsll((unsigned long long)bal) - 1;
        float4 pb = bx2[L];
        float pa = (pb.z - pb.x + 1.f) * (pb.w - pb.y + 1.f);
        if (lane == 0) kb[nkl] = pb;
        nkl++;
        if (lane == L) alive = false;
        if (alive){
          float xx1 = fmaxf(pb.x, b.x);
          float yy1 = fmaxf(pb.y, b.y);
          float xx2 = fminf(pb.z, b.z);
          float yy2 = fminf(pb.w, b.w);
          float iw = fmaxf(xx2 - xx1 + 1.f, 0.f);
          float ih = fmaxf(yy2 - yy1 + 1.f, 0.f);
          float inter = iw * ih;
          float iou = inter / (pa + ar - inter);
          if (iou > 0.7f) alive = false;
        }
      }
      if (lane == 0) nkS = nkl;
    }
    __syncthreads();
  }
  int nk = nkS;
  for (int q = tid; q < 1500; q += 256){
    int r = q / 5, c = q - r*5;
    float v = 0.f;
    if (r < nk && c > 0){
      float4 bx = kb[r];
      v = (c == 1) ? bx.x : (c == 2) ? bx.y : (c == 3) ? bx.z : bx.w;
    }
    out[q] = v;
  }
}

// ---------------- launch ----------------
extern "C" void kernel_launch(void* const* d_in, const int* in_sizes, int n_in,
                              void* d_out, int out_size, void* d_ws, size_t ws_size,
                              hipStream_t stream)
{
  const float* fm   = (const float*)d_in[0];
  const float* info = (const float*)d_in[1];
  const float* cw3  = (const float*)d_in[2];
  const float* cb3  = (const float*)d_in[3];
  const float* clw  = (const float*)d_in[4];
  const float* clb  = (const float*)d_in[5];
  const float* bbw  = (const float*)d_in[6];
  const float* bbb  = (const float*)d_in[7];
  float* out = (float*)d_out;

  char* base = (char*)d_ws;
  u32*   hist8g = (u32*)  (base + 0);          // 384*256 u32 = 393216 B
  u32*   hist2  = (u32*)  (base + 393216);     // 65536 u32  = 262144 B
  u32*   ctr    = (u32*)  (base + 655360);     // 16 u32: [0]=count [4]=finiteN
  float* Y      = (float*)(base + 655424);     // 12582912 B -> ends 13238336
  float* scores = (float*)(base + 13238336);   // 221184 B  -> ends 13459520
  float4* boxes = (float4*)(base + 13459520);  // 884736 B  -> ends 14344256
  u64*   keys   = (u64*)  (base + 14344256);   // 65536 B   -> ends 14409792
  float4* topB  = (float4*)(base + 14409792);  // 6000*16 = 96000 B -> ends 14505792
  float* topA   = (float*)(base + 14505792);   // 6000*4  = 24000 B -> ends 14529792
  unsigned short* Xih = (unsigned short*)(base + 14529792);  // 6623232 B -> ends 21153024
  unsigned short* Xil = (unsigned short*)(base + 21153024);  // 6623232 B -> ends 27776256
  unsigned short* Wh2 = (unsigned short*)(base + 27776256);  // 4718592 B -> ends 32494848
  unsigned short* Wl2 = (unsigned short*)(base + 32494848);  // 4718592 B -> ends 37213440
  float* Whd = (float*)(base + 37213440);      // 512*64 f32 -> ends 37344512
  // total ws use: ~37.3 MB

  k_cvt   <<<1168, 256, 0, stream>>>(fm, cw3, clw, bbw, Xih, Xil, Wh2, Wl2, Whd, (u32*)base);
  k_conv3 <<<dim3(16, 16), 256, 0, stream>>>(Xih, Xil, Wh2, Wl2, cb3, Y);
  k_head  <<<384, 256, 0, stream>>>(Y, Whd, clb, bbb, info, scores, boxes, hist8g);
  k_sel   <<<1,  1024, 0, stream>>>(hist8g, hist2, scores, ctr, keys);
  k_rank  <<<256, 512, 0, stream>>>(keys, ctr, boxes, topB, topA);
  k_nms3  <<<1,   256, 0, stream>>>(topB, ctr, out);
}